// Round 8
// baseline (892.307 us; speedup 1.0000x reference)
//
#include <hip/hip_runtime.h>
#include <cstdint>
#include <cstddef>

// ---------------------------------------------------------------------------
// StaticGNN fused pipeline, round 15: round-14 (best, 888.6us) +
// classifier register-prefetch (T14 async-STAGE): eab + full h2[s]/h2[d]
// rows loaded into registers at kernel entry; LDS phase-writes come from
// registers, hiding the random-gather latency under phase-1 MFMA and
// halving the number of h2 gather requests (256B full-row bursts).
// N=50000, E=400000, ND=128, ED=64, HID=128.
// ---------------------------------------------------------------------------

static inline int cdiv(int a, int b) { return (a + b - 1) / b; }

typedef __attribute__((ext_vector_type(8))) short bfrag;   // 8 bf16 (4 VGPRs)
typedef __attribute__((ext_vector_type(4))) float ffrag;   // 4 fp32 acc

__device__ __forceinline__ float bf2f(unsigned short u) {
  return __uint_as_float(((unsigned)u) << 16);
}
__device__ __forceinline__ unsigned short f2bf(float f) {
  unsigned b = __float_as_uint(f);
  return (unsigned short)((b + 0x7FFFu + ((b >> 16) & 1u)) >> 16);
}

// ---------------------------------------------------------------------------
// Weight prep: W[K][Nc] fp32 -> Wt[Nc][KC] bf16 (zero-padded K -> KC).
// ---------------------------------------------------------------------------
struct PrepJobs {
  const float* src[11];
  unsigned short* dst[11];
  int K[11], Nc[11], KC[11], ld[11];
};
__global__ void prep_bt(PrepJobs J) {
  int j = blockIdx.x;
  int K = J.K[j], Nc = J.Nc[j], KC = J.KC[j], ld = J.ld[j];
  const float* S = J.src[j];
  unsigned short* D = J.dst[j];
  for (int n = blockIdx.y; n < Nc; n += gridDim.y)
    for (int t = threadIdx.x; t < KC; t += blockDim.x) {
      float v = (t < K) ? S[(size_t)t * ld + n] : 0.f;
      D[(size_t)n * KC + t] = f2bf(v);
    }
}

// fp32 -> bf16 bulk convert (float4 -> ushort4), grid-stride
__global__ __launch_bounds__(256) void cvt_bf16(const float* __restrict__ in,
                                                unsigned short* __restrict__ out,
                                                int n4) {
  for (int i = blockIdx.x * blockDim.x + threadIdx.x; i < n4;
       i += gridDim.x * blockDim.x) {
    float4 v = ((const float4*)in)[i];
    ((ushort4*)out)[i] = make_ushort4(f2bf(v.x), f2bf(v.y), f2bf(v.z), f2bf(v.w));
  }
}

// ---------------------------------------------------------------------------
// CSR build: degree count, 3-phase parallel exclusive scan, slot scatter.
// ---------------------------------------------------------------------------
__global__ void count_deg(const int* __restrict__ src, const int* __restrict__ dst,
                          int* __restrict__ dsrc, int* __restrict__ ddst, int E) {
  int t = blockIdx.x * blockDim.x + threadIdx.x;
  if (t < E) {
    atomicAdd(&dsrc[src[t]], 1);
    atomicAdd(&ddst[dst[t]], 1);
  }
}

__global__ __launch_bounds__(256) void scan_local(
    const int* __restrict__ degA, const int* __restrict__ degB,
    int* __restrict__ rowA, int* __restrict__ rowB, int* __restrict__ bsum,
    int N, int nb) {
  __shared__ int s[256];
  int arr = blockIdx.y;
  const int* deg = arr ? degB : degA;
  int* row = arr ? rowB : rowA;
  int b = blockIdx.x;
  int i = b * 256 + threadIdx.x;
  int v = (i < N) ? deg[i] : 0;
  s[threadIdx.x] = v;
  __syncthreads();
  for (int off = 1; off < 256; off <<= 1) {
    int t = (threadIdx.x >= off) ? s[threadIdx.x - off] : 0;
    __syncthreads();
    s[threadIdx.x] += t;
    __syncthreads();
  }
  int incl = s[threadIdx.x];
  if (i < N) row[i] = incl - v;
  if (threadIdx.x == 255) bsum[arr * nb + b] = incl;
}

__global__ __launch_bounds__(1024) void scan_bsums(int* __restrict__ bsum, int nb,
                                                   int* __restrict__ rowA,
                                                   int* __restrict__ rowB, int N) {
  __shared__ int s[1024];
  int tid = threadIdx.x;
  for (int arr = 0; arr < 2; arr++) {
    int v = (tid < nb) ? bsum[arr * nb + tid] : 0;
    s[tid] = v;
    __syncthreads();
    for (int off = 1; off < 1024; off <<= 1) {
      int t = (tid >= off) ? s[tid - off] : 0;
      __syncthreads();
      s[tid] += t;
      __syncthreads();
    }
    if (tid < nb) bsum[arr * nb + tid] = s[tid] - v;
    if (tid == nb - 1) {
      int* row = arr ? rowB : rowA;
      row[N] = s[tid];
    }
    __syncthreads();
  }
}

__global__ void scan_add(int* __restrict__ rowA, int* __restrict__ rowB,
                         int* __restrict__ curA, const int* __restrict__ bsum,
                         int N, int nb) {
  int arr = blockIdx.y;
  int* row = arr ? rowB : rowA;
  int b = blockIdx.x;
  int i = b * 256 + threadIdx.x;
  if (i < N) {
    int v = row[i] + bsum[arr * nb + b];
    row[i] = v;
    if (arr == 0) curA[i] = v;
  }
}

__global__ void ext_fix(const int* __restrict__ row_dst, int* __restrict__ row_ext,
                        int* __restrict__ cur_ext, int* __restrict__ ext_eid,
                        int* __restrict__ ssrc, int* __restrict__ sdst,
                        int E, int N) {
  int i = blockIdx.x * blockDim.x + threadIdx.x;
  if (i <= N) row_ext[i] = row_dst[i] + i;
  if (i < N) {
    cur_ext[i] = row_dst[i] + i;
    int p = row_dst[i + 1] + i;
    ext_eid[p] = E + i;
    ssrc[p] = i;
    sdst[p] = i;
  }
}

__global__ void scatter_eid(const int* __restrict__ src, const int* __restrict__ dst,
                            int* __restrict__ csrc, int* __restrict__ cext,
                            int* __restrict__ esrc, int* __restrict__ ext_eid,
                            int* __restrict__ ssrc, int* __restrict__ sdst,
                            int E) {
  int t = blockIdx.x * blockDim.x + threadIdx.x;
  if (t < E) {
    int s = src[t], d = dst[t];
    int p = atomicAdd(&csrc[s], 1);
    esrc[p] = t;
    int q = atomicAdd(&cext[d], 1);
    ext_eid[q] = t;
    ssrc[q] = s;
    sdst[q] = d;
  }
}

// ---------------------------------------------------------------------------
// Virtual 3-way concatenated A operand (fp32 sources).
// ---------------------------------------------------------------------------
struct ASrc {
  const float *p0, *p1, *p2;
  int ld0, ld1, ld2, k0, k1;
};
__device__ __forceinline__ float loadA(const ASrc& a, int m, int k) {
  if (k < a.k0) return a.p0[(size_t)m * a.ld0 + k];
  if (k < a.k1) return a.p1[(size_t)m * a.ld1 + (k - a.k0)];
  return a.p2[(size_t)m * a.ld2 + (k - a.k1)];
}
__device__ __forceinline__ int regionOf(const ASrc& a, int k) {
  return k < a.k0 ? 0 : (k < a.k1 ? 1 : 2);
}

// A-staging helper: fills asb[64][72] bf16 for K-chunk kc.
template <int ABF>
__device__ __forceinline__ void stageA(
    const ASrc& A, const unsigned short* __restrict__ Abf, int lda,
    unsigned short* asb, int m0, int kc, int M, int K, int tid) {
  int row = tid & 63, kq = tid >> 6;
  int gm = m0 + row;
  if (ABF) {
    const unsigned short* rp = Abf + (size_t)gm * lda + kc + kq * 16;
    ushort4 z = make_ushort4(0, 0, 0, 0);
#pragma unroll
    for (int q = 0; q < 4; q++) {
      ushort4 v = (gm < M) ? *(const ushort4*)(rp + q * 4) : z;
      *(ushort4*)&asb[row * 72 + kq * 16 + q * 4] = v;
    }
  } else {
    bool fastc = (kc + 64 <= K) && (regionOf(A, kc) == regionOf(A, kc + 63)) &&
                 (gm < M);
    if (fastc) {
      int r = regionOf(A, kc);
      const float* p;
      int ld, koff;
      if (r == 0) { p = A.p0; ld = A.ld0; koff = 0; }
      else if (r == 1) { p = A.p1; ld = A.ld1; koff = A.k0; }
      else { p = A.p2; ld = A.ld2; koff = A.k1; }
      const float* rp = p + (size_t)gm * ld + (kc - koff) + kq * 16;
#pragma unroll
      for (int q = 0; q < 4; q++) {
        float4 v = *(const float4*)(rp + q * 4);
        *(ushort4*)&asb[row * 72 + kq * 16 + q * 4] =
            make_ushort4(f2bf(v.x), f2bf(v.y), f2bf(v.z), f2bf(v.w));
      }
    } else {
#pragma unroll
      for (int q = 0; q < 16; q++) {
        int kk = kc + kq * 16 + q;
        float v = (gm < M && kk < K) ? loadA(A, gm, kk) : 0.f;
        asb[row * 72 + kq * 16 + q] = f2bf(v);
      }
    }
  }
}

// ---------------------------------------------------------------------------
// MFMA GEMM: C[M, n0..n0+128) = act(A[M,K] @ B + bias). 64x128 tile, 4 waves.
// ---------------------------------------------------------------------------
template <int ACT, int OBF, int ABF>
__global__ __launch_bounds__(256) void gemm_mfma(
    ASrc A, const unsigned short* __restrict__ Abf, int lda,
    const unsigned short* __restrict__ Bt, int ldbt,
    const float* __restrict__ bias, void* __restrict__ Cv, int ldc, int M, int K) {
  __shared__ __align__(16) unsigned short asb[64 * 72];
  __shared__ __align__(16) unsigned short bsb[128 * 72];
  int tid = threadIdx.x;
  int m0 = blockIdx.x * 64, n0 = blockIdx.y * 128;
  int lane = tid & 63, wave = tid >> 6;
  int quad = lane >> 4, l16 = lane & 15;
  ffrag zero = {0.f, 0.f, 0.f, 0.f};
  ffrag acc[8];
#pragma unroll
  for (int t = 0; t < 8; t++) acc[t] = zero;
  int KC = (K + 63) & ~63;
  for (int kc = 0; kc < KC; kc += 64) {
    __syncthreads();
    stageA<ABF>(A, Abf, lda, asb, m0, kc, M, K, tid);
    {  // stage B chunk
      int n = tid >> 1, hf = tid & 1;
      const ushort4* rp = (const ushort4*)(Bt + (size_t)(n0 + n) * ldbt + kc + hf * 32);
      ushort4* dp = (ushort4*)&bsb[n * 72 + hf * 32];
#pragma unroll
      for (int i = 0; i < 8; i++) dp[i] = rp[i];
    }
    __syncthreads();
    int arow = wave * 16 + l16;
    bfrag a0 = *(const bfrag*)&asb[arow * 72 + quad * 8];
    bfrag a1 = *(const bfrag*)&asb[arow * 72 + 32 + quad * 8];
#pragma unroll
    for (int t = 0; t < 8; t++) {
      int bn = t * 16 + l16;
      bfrag b0 = *(const bfrag*)&bsb[bn * 72 + quad * 8];
      bfrag b1 = *(const bfrag*)&bsb[bn * 72 + 32 + quad * 8];
      acc[t] = __builtin_amdgcn_mfma_f32_16x16x32_bf16(a0, b0, acc[t], 0, 0, 0);
      acc[t] = __builtin_amdgcn_mfma_f32_16x16x32_bf16(a1, b1, acc[t], 0, 0, 0);
    }
  }
#pragma unroll
  for (int t = 0; t < 8; t++) {
    int col = n0 + t * 16 + l16;
    float bv = bias ? bias[col] : 0.f;
#pragma unroll
    for (int r = 0; r < 4; r++) {
      int row = m0 + wave * 16 + quad * 4 + r;
      if (row < M) {
        float v = acc[t][r] + bv;
        if (ACT == 1) v = fmaxf(v, 0.f);
        if (OBF)
          ((unsigned short*)Cv)[(size_t)row * ldc + col] = f2bf(v);
        else
          ((float*)Cv)[(size_t)row * ldc + col] = v;
      }
    }
  }
}

// ---------------------------------------------------------------------------
// Dual-B MFMA GEMM: stages A once per K-chunk, accumulates A@B1 and A@B2.
// ---------------------------------------------------------------------------
template <int OBF, int ABF>
__global__ __launch_bounds__(256) void gemm_dual(
    ASrc A, const unsigned short* __restrict__ Abf, int lda,
    const unsigned short* __restrict__ Bt1, const unsigned short* __restrict__ Bt2,
    int ldbt, void* __restrict__ Cv1, void* __restrict__ Cv2, int ldc,
    int M, int K) {
  __shared__ __align__(16) unsigned short asb[64 * 72];
  __shared__ __align__(16) unsigned short bsb[128 * 72];
  int tid = threadIdx.x;
  int m0 = blockIdx.x * 64, n0 = blockIdx.y * 128;
  int lane = tid & 63, wave = tid >> 6;
  int quad = lane >> 4, l16 = lane & 15;
  ffrag zero = {0.f, 0.f, 0.f, 0.f};
  ffrag acc1[8], acc2[8];
#pragma unroll
  for (int t = 0; t < 8; t++) { acc1[t] = zero; acc2[t] = zero; }
  int KC = (K + 63) & ~63;
  int arow = wave * 16 + l16;
  for (int kc = 0; kc < KC; kc += 64) {
    __syncthreads();
    stageA<ABF>(A, Abf, lda, asb, m0, kc, M, K, tid);
    {  // stage B1 chunk
      int n = tid >> 1, hf = tid & 1;
      const ushort4* rp = (const ushort4*)(Bt1 + (size_t)(n0 + n) * ldbt + kc + hf * 32);
      ushort4* dp = (ushort4*)&bsb[n * 72 + hf * 32];
#pragma unroll
      for (int i = 0; i < 8; i++) dp[i] = rp[i];
    }
    __syncthreads();
    bfrag a0 = *(const bfrag*)&asb[arow * 72 + quad * 8];
    bfrag a1 = *(const bfrag*)&asb[arow * 72 + 32 + quad * 8];
#pragma unroll
    for (int t = 0; t < 8; t++) {
      int bn = t * 16 + l16;
      bfrag b0 = *(const bfrag*)&bsb[bn * 72 + quad * 8];
      bfrag b1 = *(const bfrag*)&bsb[bn * 72 + 32 + quad * 8];
      acc1[t] = __builtin_amdgcn_mfma_f32_16x16x32_bf16(a0, b0, acc1[t], 0, 0, 0);
      acc1[t] = __builtin_amdgcn_mfma_f32_16x16x32_bf16(a1, b1, acc1[t], 0, 0, 0);
    }
    __syncthreads();  // B1 reads complete before restage
    {  // stage B2 chunk
      int n = tid >> 1, hf = tid & 1;
      const ushort4* rp = (const ushort4*)(Bt2 + (size_t)(n0 + n) * ldbt + kc + hf * 32);
      ushort4* dp = (ushort4*)&bsb[n * 72 + hf * 32];
#pragma unroll
      for (int i = 0; i < 8; i++) dp[i] = rp[i];
    }
    __syncthreads();
#pragma unroll
    for (int t = 0; t < 8; t++) {
      int bn = t * 16 + l16;
      bfrag b0 = *(const bfrag*)&bsb[bn * 72 + quad * 8];
      bfrag b1 = *(const bfrag*)&bsb[bn * 72 + 32 + quad * 8];
      acc2[t] = __builtin_amdgcn_mfma_f32_16x16x32_bf16(a0, b0, acc2[t], 0, 0, 0);
      acc2[t] = __builtin_amdgcn_mfma_f32_16x16x32_bf16(a1, b1, acc2[t], 0, 0, 0);
    }
  }
#pragma unroll
  for (int t = 0; t < 8; t++) {
    int col = n0 + t * 16 + l16;
#pragma unroll
    for (int r = 0; r < 4; r++) {
      int row = m0 + wave * 16 + quad * 4 + r;
      if (row < M) {
        if (OBF) {
          ((unsigned short*)Cv1)[(size_t)row * ldc + col] = f2bf(acc1[t][r]);
          ((unsigned short*)Cv2)[(size_t)row * ldc + col] = f2bf(acc2[t][r]);
        } else {
          ((float*)Cv1)[(size_t)row * ldc + col] = acc1[t][r];
          ((float*)Cv2)[(size_t)row * ldc + col] = acc2[t][r];
        }
      }
    }
  }
}

// ---------------------------------------------------------------------------
// gather-mean, 8B-vectorized: 2 edges per wave iteration, shfl_xor(32) combine.
// ---------------------------------------------------------------------------
__global__ __launch_bounds__(256) void gather_mean(
    const int* __restrict__ row_src, const int* __restrict__ eid_src,
    const int* __restrict__ row_ext, const int* __restrict__ ext_eid,
    const unsigned short* __restrict__ emb, const unsigned short* __restrict__ eab,
    float* __restrict__ xout, float* __restrict__ xin,
    unsigned short* __restrict__ lattrb, int N) {
  int lane = threadIdx.x & 63, wid = threadIdx.x >> 6;
  int n = blockIdx.x * 4 + wid;
  int side = blockIdx.y;
  if (n >= N) return;
  int lo, hi;
  const int* eid;
  if (side) { lo = row_ext[n]; hi = row_ext[n + 1] - 1; eid = ext_eid; }
  else { lo = row_src[n]; hi = row_src[n + 1]; eid = eid_src; }
  int half = lane >> 5;
  int l32 = lane & 31;
  int c4 = l32 * 4;
  float a0 = 0.f, a1 = 0.f, a2 = 0.f, a3 = 0.f;
  float la0 = 0.f, la1 = 0.f;
  int j = lo;
  for (; j + 1 < hi; j += 2) {
    int e = eid[j + half];
    ushort4 v = *(const ushort4*)&emb[(size_t)e * 128 + c4];
    a0 += bf2f(v.x); a1 += bf2f(v.y); a2 += bf2f(v.z); a3 += bf2f(v.w);
    if (side) {
      ushort2 u = *(const ushort2*)&eab[(size_t)e * 64 + l32 * 2];
      la0 += bf2f(u.x); la1 += bf2f(u.y);
    }
  }
  if (j < hi && half == 0) {  // odd tail: lanes 0-31 only
    int e = eid[j];
    ushort4 v = *(const ushort4*)&emb[(size_t)e * 128 + c4];
    a0 += bf2f(v.x); a1 += bf2f(v.y); a2 += bf2f(v.z); a3 += bf2f(v.w);
    if (side) {
      ushort2 u = *(const ushort2*)&eab[(size_t)e * 64 + l32 * 2];
      la0 += bf2f(u.x); la1 += bf2f(u.y);
    }
  }
  a0 += __shfl_xor(a0, 32);
  a1 += __shfl_xor(a1, 32);
  a2 += __shfl_xor(a2, 32);
  a3 += __shfl_xor(a3, 32);
  if (side) {
    la0 += __shfl_xor(la0, 32);
    la1 += __shfl_xor(la1, 32);
  }
  float r = 1.f / fmaxf((float)(hi - lo), 1.f);
  if (half == 0) {
    float* ob = side ? xin : xout;
    *(float4*)&ob[(size_t)n * 128 + c4] =
        make_float4(a0 * r, a1 * r, a2 * r, a3 * r);
    if (side)
      *(ushort2*)&lattrb[(size_t)n * 64 + l32 * 2] =
          make_ushort2(f2bf(la0 * r), f2bf(la1 * r));
  }
}

// ---------------------------------------------------------------------------
// attn_logits_mfma<H> — dst-sorted edges; stores a = exp(min(logit,60)) at
// sorted position j. ssrc/sdst give sequential index reads.
// ---------------------------------------------------------------------------
template <int H>
__global__ __launch_bounds__(256) void attn_logits_mfma(
    const unsigned short* __restrict__ xl, const unsigned short* __restrict__ xr,
    const int* __restrict__ ssrc, const int* __restrict__ sdst,
    const unsigned short* __restrict__ eab, const unsigned short* __restrict__ lattrb,
    const int* __restrict__ ext_eid,
    const unsigned short* __restrict__ wet, const float* __restrict__ att,
    float* __restrict__ lg, int E, int N) {
  constexpr int HC = H * 128;
  __shared__ __align__(16) unsigned short asb[64 * 72];
  __shared__ __align__(16) unsigned short bsb[128 * 72];  // reused as Cs[64][136]
  __shared__ float atts[128];
  __shared__ int sidx[64], didx[64];
  unsigned short* Cs = bsb;
  int tid = threadIdx.x;
  int E2 = E + N;
  int i0 = blockIdx.x * 64;
  int lane = tid & 63, wave = tid >> 6, quad = lane >> 4, l16 = lane & 15;
  if (tid < 64) {
    int j = i0 + tid;
    sidx[tid] = (j < E2) ? ssrc[j] : 0;
    didx[tid] = (j < E2) ? sdst[j] : 0;
  }
  {  // stage A once (bf16 sources, dst-sorted edge order)
    int row = tid & 63, kq = tid >> 6;
    int j = i0 + row;
    if (j < E2) {
      int e = ext_eid[j];
      const unsigned short* ap =
          (e < E) ? eab + (size_t)e * 64 : lattrb + (size_t)(e - E) * 64;
      const ushort4* rp = (const ushort4*)(ap + kq * 16);
#pragma unroll
      for (int q = 0; q < 4; q++)
        *(ushort4*)&asb[row * 72 + kq * 16 + q * 4] = rp[q];
    } else {
      ushort4 z = make_ushort4(0, 0, 0, 0);
#pragma unroll
      for (int q = 0; q < 4; q++) *(ushort4*)&asb[row * 72 + kq * 16 + q * 4] = z;
    }
  }
  int er = tid >> 4, cc = tid & 15;
  ffrag zero = {0.f, 0.f, 0.f, 0.f};
  for (int head = 0; head < H; head++) {
    int n0 = head * 128;
    __syncthreads();
    if (tid < 128) atts[tid] = att[n0 + tid];
    {
      int n = tid >> 1, hf = tid & 1;
      const ushort4* rp = (const ushort4*)(wet + (size_t)(n0 + n) * 64 + hf * 32);
      ushort4* dp = (ushort4*)&bsb[n * 72 + hf * 32];
#pragma unroll
      for (int i = 0; i < 8; i++) dp[i] = rp[i];
    }
    __syncthreads();
    int arow = wave * 16 + l16;
    bfrag a0 = *(const bfrag*)&asb[arow * 72 + quad * 8];
    bfrag a1 = *(const bfrag*)&asb[arow * 72 + 32 + quad * 8];
    ffrag acc[8];
#pragma unroll
    for (int t = 0; t < 8; t++) {
      acc[t] = zero;
      int bn = t * 16 + l16;
      bfrag b0 = *(const bfrag*)&bsb[bn * 72 + quad * 8];
      bfrag b1 = *(const bfrag*)&bsb[bn * 72 + 32 + quad * 8];
      acc[t] = __builtin_amdgcn_mfma_f32_16x16x32_bf16(a0, b0, acc[t], 0, 0, 0);
      acc[t] = __builtin_amdgcn_mfma_f32_16x16x32_bf16(a1, b1, acc[t], 0, 0, 0);
    }
    __syncthreads();
    {
      int rb = wave * 16 + quad * 4;
#pragma unroll
      for (int t = 0; t < 8; t++)
#pragma unroll
        for (int r = 0; r < 4; r++)
          Cs[(rb + r) * 136 + t * 16 + l16] = f2bf(acc[t][r]);
    }
    __syncthreads();
#pragma unroll
    for (int i2 = 0; i2 < 4; i2++) {
      int r = er * 4 + i2;
      int gi = i0 + r;
      float ps = 0.f;
      if (gi < E2) {
        int s = sidx[r], d = didx[r];
#pragma unroll
        for (int h = 0; h < 2; h++) {
          int c = h * 64 + cc * 4;
          ushort4 mv = *(const ushort4*)&Cs[r * 136 + c];
          ushort4 xlu = *(const ushort4*)&xl[(size_t)s * HC + n0 + c];
          ushort4 xru = *(const ushort4*)&xr[(size_t)d * HC + n0 + c];
          float e0 = bf2f(mv.x) + bf2f(xlu.x) + bf2f(xru.x);
          float e1 = bf2f(mv.y) + bf2f(xlu.y) + bf2f(xru.y);
          float e2 = bf2f(mv.z) + bf2f(xlu.z) + bf2f(xru.z);
          float e3 = bf2f(mv.w) + bf2f(xlu.w) + bf2f(xru.w);
          e0 = e0 > 0.f ? e0 : 0.2f * e0;
          e1 = e1 > 0.f ? e1 : 0.2f * e1;
          e2 = e2 > 0.f ? e2 : 0.2f * e2;
          e3 = e3 > 0.f ? e3 : 0.2f * e3;
          ps += e0 * atts[c + 0] + e1 * atts[c + 1] + e2 * atts[c + 2] +
                e3 * atts[c + 3];
        }
      }
      ps += __shfl_xor(ps, 1);
      ps += __shfl_xor(ps, 2);
      ps += __shfl_xor(ps, 4);
      ps += __shfl_xor(ps, 8);
      if (cc == 0 && gi < E2)
        lg[(size_t)gi * H + head] = __expf(fminf(ps, 60.f));
    }
  }
}

// ---------------------------------------------------------------------------
// attn_fused<H> — lg holds pre-exponentiated a at sorted position j; ssrc
// gives the source node sequentially (no dependent random index load).
// ---------------------------------------------------------------------------
template <int H>
__global__ __launch_bounds__(256) void attn_fused(
    const unsigned short* __restrict__ xl, const float* __restrict__ lg,
    const int* __restrict__ row_ext, const int* __restrict__ ssrc,
    const float* __restrict__ bias,
    const float* __restrict__ gam, const float* __restrict__ bet,
    unsigned short* __restrict__ hout, int E, int N) {
  constexpr int HC = H * 128;
  constexpr int CPL = HC / 64;
  int lane = threadIdx.x & 63, wid = threadIdx.x >> 6;
  int n = blockIdx.x * 4 + wid;
  if (n >= N) return;
  int lo = row_ext[n], hi = row_ext[n + 1];
  int myh = (H == 2) ? (lane >> 5) : 0;
  int colbase = (H == 2) ? (myh * 128 + (lane & 31) * 4) : (lane * 2);
  float asum = 0.f;
  float acc[CPL] = {};
  for (int j = lo; j < hi; j++) {
    int s = ssrc[j];
    float a = lg[(size_t)j * H + myh];
    asum += a;
    const unsigned short* xp = &xl[(size_t)s * HC + colbase];
    if (H == 2) {
      ushort4 u = *(const ushort4*)xp;
      acc[0] += a * bf2f(u.x);
      acc[1] += a * bf2f(u.y);
      acc[2] += a * bf2f(u.z);
      acc[3] += a * bf2f(u.w);
    } else {
      ushort2 u = *(const ushort2*)xp;
      acc[0] += a * bf2f(u.x);
      acc[1] += a * bf2f(u.y);
    }
  }
  float inv = 1.f / fmaxf(asum, 1e-16f);
#pragma unroll
  for (int k = 0; k < CPL; k++) acc[k] *= inv;
  int ch;
  if (H == 2) {
#pragma unroll
    for (int k = 0; k < CPL; k++) acc[k] = (acc[k] + __shfl_xor(acc[k], 32)) * 0.5f;
    ch = (lane & 31) * CPL;
  } else {
    ch = lane * CPL;
  }
#pragma unroll
  for (int k = 0; k < CPL; k++) acc[k] += bias[ch + k];
  float s = 0.f;
#pragma unroll
  for (int k = 0; k < CPL; k++) s += acc[k];
#pragma unroll
  for (int mm = 1; mm < 64; mm <<= 1) s += __shfl_xor(s, mm);
  constexpr float dupn = (H == 2) ? 256.f : 128.f;
  float mu = s / dupn;
  float vs = 0.f;
#pragma unroll
  for (int k = 0; k < CPL; k++) {
    acc[k] -= mu;
    vs += acc[k] * acc[k];
  }
#pragma unroll
  for (int mm = 1; mm < 64; mm <<= 1) vs += __shfl_xor(vs, mm);
  float rstd = rsqrtf(vs / dupn + 1e-5f);
  float y[CPL];
#pragma unroll
  for (int k = 0; k < CPL; k++) {
    float v = acc[k] * rstd * gam[ch + k] + bet[ch + k];
    y[k] = v > 0.f ? v : expm1f(v);
  }
  if (H == 2) {
    if (lane < 32)
      *(ushort4*)&hout[(size_t)n * 128 + ch] =
          make_ushort4(f2bf(y[0]), f2bf(y[1]), f2bf(y[2]), f2bf(y[3]));
  } else {
    *(ushort2*)&hout[(size_t)n * 128 + ch] = make_ushort2(f2bf(y[0]), f2bf(y[1]));
  }
}

// ---------------------------------------------------------------------------
// classifier_mfma — fully fused with register prefetch (T14): eab + full
// h2[s]/h2[d] rows loaded to regs at entry; LDS phase-writes from regs.
// c1 = ea@c1wc + h2[s]@c1wa + h2[d]@c1wb (fp32 MFMA accumulation), then
// relu -> c2 -> relu -> c3. src-sorted edges; out scattered via eidx.
// ---------------------------------------------------------------------------
__global__ __launch_bounds__(256) void classifier_mfma(
    const unsigned short* __restrict__ eab, const unsigned short* __restrict__ h2b,
    const int* __restrict__ eid_src,
    const int* __restrict__ src, const int* __restrict__ dst,
    const unsigned short* __restrict__ c1wct, const unsigned short* __restrict__ c1wat,
    const unsigned short* __restrict__ c1wbt,
    const float* __restrict__ c1b, const unsigned short* __restrict__ c2t,
    const float* __restrict__ c2b, const float* __restrict__ c3w,
    const float* __restrict__ c3b, float* __restrict__ out, int E) {
  __shared__ __align__(16) unsigned short asb[64 * 72];
  __shared__ __align__(16) unsigned short bsb[128 * 72];  // also c2 [64][136]
  __shared__ __align__(16) unsigned short t1s[64 * 136];
  __shared__ float c1bs[128];
  __shared__ float c2bs[64], c3ws[64];
  __shared__ int eidx[64];
  int tid = threadIdx.x;
  int e0 = blockIdx.x * 64;
  int lane = tid & 63, wave = tid >> 6, quad = lane >> 4, l16 = lane & 15;
  int row = tid & 63, kq = tid >> 6;
  // ---- register prefetch (issued before anything else) ----
  int jj = e0 + row;
  int e = (jj < E) ? eid_src[jj] : -1;
  int esafe = (e >= 0) ? e : 0;
  int s = (e >= 0) ? src[e] : 0;
  int d = (e >= 0) ? dst[e] : 0;
  ushort4 ereg[4], sreg[8], dreg[8];
  {
    const ushort4* ep = (const ushort4*)(eab + (size_t)esafe * 64 + kq * 16);
#pragma unroll
    for (int q = 0; q < 4; q++) ereg[q] = ep[q];
    const ushort4* sp = (const ushort4*)(h2b + (size_t)s * 128 + kq * 32);
    const ushort4* dp2 = (const ushort4*)(h2b + (size_t)d * 128 + kq * 32);
#pragma unroll
    for (int q = 0; q < 8; q++) { sreg[q] = sp[q]; dreg[q] = dp2[q]; }
  }
  if (tid < 128) c1bs[tid] = c1b[tid];
  if (tid < 64) {
    c2bs[tid] = c2b[tid];
    c3ws[tid] = c3w[tid];
    int j2 = e0 + tid;
    eidx[tid] = (j2 < E) ? eid_src[j2] : -1;
  }
  ffrag zero = {0.f, 0.f, 0.f, 0.f};
  ffrag acc[8];
#pragma unroll
  for (int t = 0; t < 8; t++) acc[t] = zero;
  int arow = wave * 16 + l16;
  // ---- phase 1: ea @ c1wc (K=64); asb written from ereg ----
  {
#pragma unroll
    for (int q = 0; q < 4; q++)
      *(ushort4*)&asb[row * 72 + kq * 16 + q * 4] = ereg[q];
    int n = tid >> 1, hf = tid & 1;
    const ushort4* rp2 = (const ushort4*)(c1wct + (size_t)n * 64 + hf * 32);
    ushort4* dp = (ushort4*)&bsb[n * 72 + hf * 32];
#pragma unroll
    for (int i = 0; i < 8; i++) dp[i] = rp2[i];
  }
  __syncthreads();
  {
    bfrag a0 = *(const bfrag*)&asb[arow * 72 + quad * 8];
    bfrag a1 = *(const bfrag*)&asb[arow * 72 + 32 + quad * 8];
#pragma unroll
    for (int t = 0; t < 8; t++) {
      int bn = t * 16 + l16;
      bfrag b0 = *(const bfrag*)&bsb[bn * 72 + quad * 8];
      bfrag b1 = *(const bfrag*)&bsb[bn * 72 + 32 + quad * 8];
      acc[t] = __builtin_amdgcn_mfma_f32_16x16x32_bf16(a0, b0, acc[t], 0, 0, 0);
      acc[t] = __builtin_amdgcn_mfma_f32_16x16x32_bf16(a1, b1, acc[t], 0, 0, 0);
    }
  }
  // ---- phases 2,3: h2[s]@c1wa, h2[d]@c1wb — K=128 in 64-col halves, A from
  // regs (ph/kc compile-time unrolled so sreg/dreg stay in registers) ----
#pragma unroll
  for (int ph = 0; ph < 2; ph++) {
#pragma unroll
    for (int kc = 0; kc < 2; kc++) {
      __syncthreads();  // prior MFMA reads of asb/bsb complete
      // thread (row,kq) holds h2 cols [kq*32, kq*32+32); half kc = cols
      // [kc*64, kc*64+64) -> threads with kq>>1 == kc write this half.
      if ((kq >> 1) == kc) {
        ushort4* ap = (ushort4*)&asb[row * 72 + (kq & 1) * 32];
#pragma unroll
        for (int q = 0; q < 8; q++) ap[q] = ph ? dreg[q] : sreg[q];
      }
      {  // stage B half: Wt[n][kc*64 .. +64)
        int n = tid >> 1, hf = tid & 1;
        const unsigned short* Wt = ph ? c1wbt : c1wat;
        const ushort4* rp2 =
            (const ushort4*)(Wt + (size_t)n * 128 + kc * 64 + hf * 32);
        ushort4* dp = (ushort4*)&bsb[n * 72 + hf * 32];
#pragma unroll
        for (int i = 0; i < 8; i++) dp[i] = rp2[i];
      }
      __syncthreads();
      bfrag a0 = *(const bfrag*)&asb[arow * 72 + quad * 8];
      bfrag a1 = *(const bfrag*)&asb[arow * 72 + 32 + quad * 8];
#pragma unroll
      for (int t = 0; t < 8; t++) {
        int bn = t * 16 + l16;
        bfrag b0 = *(const bfrag*)&bsb[bn * 72 + quad * 8];
        bfrag b1 = *(const bfrag*)&bsb[bn * 72 + 32 + quad * 8];
        acc[t] = __builtin_amdgcn_mfma_f32_16x16x32_bf16(a0, b0, acc[t], 0, 0, 0);
        acc[t] = __builtin_amdgcn_mfma_f32_16x16x32_bf16(a1, b1, acc[t], 0, 0, 0);
      }
    }
  }
  __syncthreads();
  // ---- c1 epilogue -> t1s bf16; stage c2t into bsb ----
  {
    int rb = wave * 16 + quad * 4;
#pragma unroll
    for (int t = 0; t < 8; t++) {
      int col = t * 16 + l16;
#pragma unroll
      for (int r = 0; r < 4; r++) {
        float v = acc[t][r] + c1bs[col];
        t1s[(rb + r) * 136 + col] = f2bf(fmaxf(v, 0.f));
      }
    }
    int n = tid >> 2, qq = tid & 3;
    const ushort4* rp = (const ushort4*)(c2t + (size_t)n * 128 + qq * 32);
    ushort4* dp = (ushort4*)&bsb[n * 136 + qq * 32];
#pragma unroll
    for (int i = 0; i < 8; i++) dp[i] = rp[i];
  }
  __syncthreads();
  {
    bfrag pa[4];
#pragma unroll
    for (int kc = 0; kc < 4; kc++)
      pa[kc] = *(const bfrag*)&t1s[arow * 136 + kc * 32 + quad * 8];
    ffrag acc2[4];
#pragma unroll
    for (int t = 0; t < 4; t++) {
      acc2[t] = zero;
      int bn = t * 16 + l16;
#pragma unroll
      for (int kc = 0; kc < 4; kc++) {
        bfrag b = *(const bfrag*)&bsb[bn * 136 + kc * 32 + quad * 8];
        acc2[t] = __builtin_amdgcn_mfma_f32_16x16x32_bf16(pa[kc], b, acc2[t], 0, 0, 0);
      }
    }
    float c3b0 = c3b[0];
    float rsum[4] = {0.f, 0.f, 0.f, 0.f};
#pragma unroll
    for (int t = 0; t < 4; t++) {
      int col = t * 16 + l16;
      float cb = c2bs[col], cw = c3ws[col];
#pragma unroll
      for (int r = 0; r < 4; r++)
        rsum[r] += fmaxf(acc2[t][r] + cb, 0.f) * cw;
    }
#pragma unroll
    for (int r = 0; r < 4; r++) {
      rsum[r] += __shfl_xor(rsum[r], 1);
      rsum[r] += __shfl_xor(rsum[r], 2);
      rsum[r] += __shfl_xor(rsum[r], 4);
      rsum[r] += __shfl_xor(rsum[r], 8);
    }
    if (l16 == 0) {
#pragma unroll
      for (int r = 0; r < 4; r++) {
        int e2 = eidx[wave * 16 + quad * 4 + r];
        if (e2 >= 0) out[e2] = rsum[r] + c3b0;
      }
    }
  }
}

// ---------------------------------------------------------------------------
extern "C" void kernel_launch(void* const* d_in, const int* in_sizes, int n_in,
                              void* d_out, int out_size, void* d_ws, size_t ws_size,
                              hipStream_t stream) {
  const int N = in_sizes[1] / 2;   // node_stats [N,2]
  const int E = in_sizes[3] / 64;  // edge_attr [E,64]
  const int E2 = E + N;
  const int nb = cdiv(N, 256);     // scan blocks per array (<=1024)

  const float* node_stats = (const float*)d_in[1];
  const int* src = (const int*)d_in[2];
  const int* dst = (const int*)d_in[2] + E;
  const float* edge_attr = (const float*)d_in[3];
  const float* epw = (const float*)d_in[4];
  const float* epb = (const float*)d_in[5];
  const float* g1wl = (const float*)d_in[6];
  const float* g1wr = (const float*)d_in[7];
  const float* g1we = (const float*)d_in[8];
  const float* g1att = (const float*)d_in[9];
  const float* g1b = (const float*)d_in[10];
  const float* n1g = (const float*)d_in[11];
  const float* n1b = (const float*)d_in[12];
  const float* g2wl = (const float*)d_in[13];
  const float* g2wr = (const float*)d_in[14];
  const float* g2we = (const float*)d_in[15];
  const float* g2att = (const float*)d_in[16];
  const float* g2b = (const float*)d_in[17];
  const float* n2g = (const float*)d_in[18];
  const float* n2b = (const float*)d_in[19];
  const float* c1w = (const float*)d_in[20];
  const float* c1b = (const float*)d_in[21];
  const float* c2w = (const float*)d_in[22];
  const float* c2b = (const float*)d_in[23];
  const float* c3w = (const float*)d_in[24];
  const float* c3b = (const float*)d_in[25];
  float* out = (float*)d_out;

  // workspace arena (float units)
  float* w = (float*)d_ws;
  size_t o = 0;
  auto alloc = [&](size_t n) { float* p = w + o; o += n; return p; };
  float* xout = alloc((size_t)N * 128);
  float* xin = alloc((size_t)N * 128);
  float* lattr = alloc((size_t)N * 64);  // used as bf16 [N][64]
  float* lg = alloc((size_t)E2 * 2);
  int* row_src = (int*)alloc((size_t)(N + 1));
  int* row_dst = (int*)alloc((size_t)(N + 1));
  int* row_ext = (int*)alloc((size_t)(N + 1));
  int* deg_src = (int*)alloc((size_t)N);  // deg pair contiguous (memset)
  int* deg_dst = (int*)alloc((size_t)N);
  int* cur_src = (int*)alloc((size_t)N);
  int* cur_ext = (int*)alloc((size_t)N);
  int* eid_src = (int*)alloc((size_t)E);
  int* ext_eid = (int*)alloc((size_t)E2);
  int* ssrc = (int*)alloc((size_t)E2);
  int* sdst = (int*)alloc((size_t)E2);
  int* bsum = (int*)alloc((size_t)2 * 1024);
  unsigned short* wb = (unsigned short*)alloc(140000);  // bf16 weight arena
  unsigned short* eab = (unsigned short*)alloc((size_t)E * 32);  // edge_attr bf16
  float* R = alloc((size_t)E * 64);  // bf16 feature arena (E*128 ushorts)
  unsigned short* Ru = (unsigned short*)R;
  unsigned short* emb = Ru;                                // E*128
  unsigned short* xl1b = Ru;                               // N*256 (emb dead)
  unsigned short* xr1b = Ru + (size_t)N * 256;             // N*256
  unsigned short* h1b = Ru + (size_t)N * 512;              // N*128
  unsigned short* xl2b = Ru + (size_t)N * 640;             // N*128
  unsigned short* xr2b = Ru + (size_t)N * 768;             // N*128
  unsigned short* h2b = Ru + (size_t)N * 896;              // N*128
  unsigned short* lattrb = (unsigned short*)lattr;

  // bf16 transposed weights
  unsigned short* epwt = wb + 0;        // [128][64]
  unsigned short* g1wlt = wb + 8192;    // [256][320]
  unsigned short* g1wrt = wb + 90112;   // [256][320]
  unsigned short* g1wet = wb + 172032;  // [256][64]
  unsigned short* g2wlt = wb + 188416;  // [128][128]
  unsigned short* g2wrt = wb + 204800;  // [128][128]
  unsigned short* g2wet = wb + 221184;  // [128][64]
  unsigned short* c1wat = wb + 229376;  // [128][128]
  unsigned short* c1wbt = wb + 245760;  // [128][128]
  unsigned short* c1wct = wb + 262144;  // [128][64]
  unsigned short* c2t = wb + 270336;    // [64][128]

  // ---- stage -1: weight prep + bf16 edge_attr ----
  cvt_bf16<<<2048, 256, 0, stream>>>(edge_attr, eab, E * 16);
  PrepJobs J;
  auto setj = [&](int i, const float* s, unsigned short* d2, int K, int Nc,
                  int KC, int ld) {
    J.src[i] = s; J.dst[i] = d2; J.K[i] = K; J.Nc[i] = Nc; J.KC[i] = KC; J.ld[i] = ld;
  };
  setj(0, epw, epwt, 64, 128, 64, 128);
  setj(1, g1wl, g1wlt, 258, 256, 320, 256);
  setj(2, g1wr, g1wrt, 258, 256, 320, 256);
  setj(3, g1we, g1wet, 64, 256, 64, 256);
  setj(4, g2wl, g2wlt, 128, 128, 128, 128);
  setj(5, g2wr, g2wrt, 128, 128, 128, 128);
  setj(6, g2we, g2wet, 64, 128, 64, 128);
  setj(7, c1w, c1wat, 128, 128, 128, 128);
  setj(8, c1w + 128 * 128, c1wbt, 128, 128, 128, 128);
  setj(9, c1w + 256 * 128, c1wct, 64, 128, 64, 128);
  setj(10, c2w, c2t, 128, 64, 128, 64);
  prep_bt<<<dim3(11, 32), 256, 0, stream>>>(J);

  // ---- stage 0: CSR (src) + extended dst CSR (parallel scan) ----
  hipMemsetAsync(deg_src, 0, (size_t)2 * N * sizeof(int), stream);
  count_deg<<<cdiv(E, 256), 256, 0, stream>>>(src, dst, deg_src, deg_dst, E);
  scan_local<<<dim3(nb, 2), 256, 0, stream>>>(deg_src, deg_dst, row_src, row_dst,
                                              bsum, N, nb);
  scan_bsums<<<1, 1024, 0, stream>>>(bsum, nb, row_src, row_dst, N);
  scan_add<<<dim3(nb, 2), 256, 0, stream>>>(row_src, row_dst, cur_src, bsum, N, nb);
  ext_fix<<<cdiv(N + 1, 256), 256, 0, stream>>>(row_dst, row_ext, cur_ext,
                                                ext_eid, ssrc, sdst, E, N);
  scatter_eid<<<cdiv(E, 256), 256, 0, stream>>>(src, dst, cur_src, cur_ext,
                                                eid_src, ext_eid, ssrc, sdst, E);

  ASrc dummy{nullptr, nullptr, nullptr, 0, 0, 0, 0, 0};

  // ---- stage 1: emb = relu(ea@epw+epb) bf16; gather means ----
  gemm_mfma<1, 1, 1><<<dim3(cdiv(E, 64), 1), 256, 0, stream>>>(
      dummy, eab, 64, epwt, 64, epb, emb, 128, E, 64);
  gather_mean<<<dim3(cdiv(N, 4), 2), 256, 0, stream>>>(
      row_src, eid_src, row_ext, ext_eid, emb, eab, xout, xin, lattrb, N);

  // ---- stage 2: xl1/xr1 (bf16) = xi @ g1wl / g1wr — dual-B, A staged once ----
  {
    ASrc a{xout, xin, node_stats, 128, 128, 2, 128, 256};
    dim3 g(cdiv(N, 64), 2);
    gemm_dual<1, 0><<<g, 256, 0, stream>>>(a, nullptr, 0, g1wlt, g1wrt, 320,
                                           xl1b, xr1b, 256, N, 258);
  }

  // ---- stage 3: GATv2 layer 1 (H=2) ----
  attn_logits_mfma<2><<<cdiv(E2, 64), 256, 0, stream>>>(
      xl1b, xr1b, ssrc, sdst, eab, lattrb, ext_eid, g1wet, g1att, lg, E, N);
  attn_fused<2><<<cdiv(N, 4), 256, 0, stream>>>(xl1b, lg, row_ext, ssrc,
                                                g1b, n1g, n1b, h1b, E, N);

  // ---- stage 4: xl2/xr2 (bf16) = h1 @ g2wl / g2wr — dual-B ----
  {
    dim3 g(cdiv(N, 64), 1);
    gemm_dual<1, 1><<<g, 256, 0, stream>>>(dummy, h1b, 128, g2wlt, g2wrt, 128,
                                           xl2b, xr2b, 128, N, 128);
  }

  // ---- stage 5: GATv2 layer 2 (H=1) ----
  attn_logits_mfma<1><<<cdiv(E2, 64), 256, 0, stream>>>(
      xl2b, xr2b, ssrc, sdst, eab, lattrb, ext_eid, g2wet, g2att, lg, E, N);
  attn_fused<1><<<cdiv(N, 4), 256, 0, stream>>>(xl2b, lg, row_ext, ssrc,
                                                g2b, n2g, n2b, h2b, E, N);

  // ---- stage 6: classifier, fully fused with register prefetch ----
  classifier_mfma<<<cdiv(E, 64), 256, 0, stream>>>(
      eab, h2b, eid_src, src, dst, c1wct, c1wat, c1wbt, c1b, c2t, c2b, c3w,
      c3b, out, E);
}

// Round 9
// 887.577 us; speedup vs baseline: 1.0053x; 1.0053x over previous
//
#include <hip/hip_runtime.h>
#include <cstdint>
#include <cstddef>

// ---------------------------------------------------------------------------
// StaticGNN fused pipeline, round 16: round-14 structure (best, 888.6us) +
// classifier LDS union-arena: {asb,bsb} (phases) alias {t1s,c2s} (epilogue),
// cutting LDS 47KB -> ~37KB => 4 blocks/CU (occupancy 30%->~45%) for the
// latency-bound classifier. Round-15's register prefetch REVERTED (regressed
// 111->122us: extra VGPR wait-wall, no occupancy gain).
// N=50000, E=400000, ND=128, ED=64, HID=128.
// ---------------------------------------------------------------------------

static inline int cdiv(int a, int b) { return (a + b - 1) / b; }

typedef __attribute__((ext_vector_type(8))) short bfrag;   // 8 bf16 (4 VGPRs)
typedef __attribute__((ext_vector_type(4))) float ffrag;   // 4 fp32 acc

__device__ __forceinline__ float bf2f(unsigned short u) {
  return __uint_as_float(((unsigned)u) << 16);
}
__device__ __forceinline__ unsigned short f2bf(float f) {
  unsigned b = __float_as_uint(f);
  return (unsigned short)((b + 0x7FFFu + ((b >> 16) & 1u)) >> 16);
}

// ---------------------------------------------------------------------------
// Weight prep: W[K][Nc] fp32 -> Wt[Nc][KC] bf16 (zero-padded K -> KC).
// ---------------------------------------------------------------------------
struct PrepJobs {
  const float* src[11];
  unsigned short* dst[11];
  int K[11], Nc[11], KC[11], ld[11];
};
__global__ void prep_bt(PrepJobs J) {
  int j = blockIdx.x;
  int K = J.K[j], Nc = J.Nc[j], KC = J.KC[j], ld = J.ld[j];
  const float* S = J.src[j];
  unsigned short* D = J.dst[j];
  for (int n = blockIdx.y; n < Nc; n += gridDim.y)
    for (int t = threadIdx.x; t < KC; t += blockDim.x) {
      float v = (t < K) ? S[(size_t)t * ld + n] : 0.f;
      D[(size_t)n * KC + t] = f2bf(v);
    }
}

// fp32 -> bf16 bulk convert (float4 -> ushort4), grid-stride
__global__ __launch_bounds__(256) void cvt_bf16(const float* __restrict__ in,
                                                unsigned short* __restrict__ out,
                                                int n4) {
  for (int i = blockIdx.x * blockDim.x + threadIdx.x; i < n4;
       i += gridDim.x * blockDim.x) {
    float4 v = ((const float4*)in)[i];
    ((ushort4*)out)[i] = make_ushort4(f2bf(v.x), f2bf(v.y), f2bf(v.z), f2bf(v.w));
  }
}

// ---------------------------------------------------------------------------
// CSR build: degree count, 3-phase parallel exclusive scan, slot scatter.
// ---------------------------------------------------------------------------
__global__ void count_deg(const int* __restrict__ src, const int* __restrict__ dst,
                          int* __restrict__ dsrc, int* __restrict__ ddst, int E) {
  int t = blockIdx.x * blockDim.x + threadIdx.x;
  if (t < E) {
    atomicAdd(&dsrc[src[t]], 1);
    atomicAdd(&ddst[dst[t]], 1);
  }
}

__global__ __launch_bounds__(256) void scan_local(
    const int* __restrict__ degA, const int* __restrict__ degB,
    int* __restrict__ rowA, int* __restrict__ rowB, int* __restrict__ bsum,
    int N, int nb) {
  __shared__ int s[256];
  int arr = blockIdx.y;
  const int* deg = arr ? degB : degA;
  int* row = arr ? rowB : rowA;
  int b = blockIdx.x;
  int i = b * 256 + threadIdx.x;
  int v = (i < N) ? deg[i] : 0;
  s[threadIdx.x] = v;
  __syncthreads();
  for (int off = 1; off < 256; off <<= 1) {
    int t = (threadIdx.x >= off) ? s[threadIdx.x - off] : 0;
    __syncthreads();
    s[threadIdx.x] += t;
    __syncthreads();
  }
  int incl = s[threadIdx.x];
  if (i < N) row[i] = incl - v;
  if (threadIdx.x == 255) bsum[arr * nb + b] = incl;
}

__global__ __launch_bounds__(1024) void scan_bsums(int* __restrict__ bsum, int nb,
                                                   int* __restrict__ rowA,
                                                   int* __restrict__ rowB, int N) {
  __shared__ int s[1024];
  int tid = threadIdx.x;
  for (int arr = 0; arr < 2; arr++) {
    int v = (tid < nb) ? bsum[arr * nb + tid] : 0;
    s[tid] = v;
    __syncthreads();
    for (int off = 1; off < 1024; off <<= 1) {
      int t = (tid >= off) ? s[tid - off] : 0;
      __syncthreads();
      s[tid] += t;
      __syncthreads();
    }
    if (tid < nb) bsum[arr * nb + tid] = s[tid] - v;
    if (tid == nb - 1) {
      int* row = arr ? rowB : rowA;
      row[N] = s[tid];
    }
    __syncthreads();
  }
}

__global__ void scan_add(int* __restrict__ rowA, int* __restrict__ rowB,
                         int* __restrict__ curA, const int* __restrict__ bsum,
                         int N, int nb) {
  int arr = blockIdx.y;
  int* row = arr ? rowB : rowA;
  int b = blockIdx.x;
  int i = b * 256 + threadIdx.x;
  if (i < N) {
    int v = row[i] + bsum[arr * nb + b];
    row[i] = v;
    if (arr == 0) curA[i] = v;
  }
}

__global__ void ext_fix(const int* __restrict__ row_dst, int* __restrict__ row_ext,
                        int* __restrict__ cur_ext, int* __restrict__ ext_eid,
                        int* __restrict__ ssrc, int* __restrict__ sdst,
                        int E, int N) {
  int i = blockIdx.x * blockDim.x + threadIdx.x;
  if (i <= N) row_ext[i] = row_dst[i] + i;
  if (i < N) {
    cur_ext[i] = row_dst[i] + i;
    int p = row_dst[i + 1] + i;
    ext_eid[p] = E + i;
    ssrc[p] = i;
    sdst[p] = i;
  }
}

__global__ void scatter_eid(const int* __restrict__ src, const int* __restrict__ dst,
                            int* __restrict__ csrc, int* __restrict__ cext,
                            int* __restrict__ esrc, int* __restrict__ ext_eid,
                            int* __restrict__ ssrc, int* __restrict__ sdst,
                            int E) {
  int t = blockIdx.x * blockDim.x + threadIdx.x;
  if (t < E) {
    int s = src[t], d = dst[t];
    int p = atomicAdd(&csrc[s], 1);
    esrc[p] = t;
    int q = atomicAdd(&cext[d], 1);
    ext_eid[q] = t;
    ssrc[q] = s;
    sdst[q] = d;
  }
}

// ---------------------------------------------------------------------------
// Virtual 3-way concatenated A operand (fp32 sources).
// ---------------------------------------------------------------------------
struct ASrc {
  const float *p0, *p1, *p2;
  int ld0, ld1, ld2, k0, k1;
};
__device__ __forceinline__ float loadA(const ASrc& a, int m, int k) {
  if (k < a.k0) return a.p0[(size_t)m * a.ld0 + k];
  if (k < a.k1) return a.p1[(size_t)m * a.ld1 + (k - a.k0)];
  return a.p2[(size_t)m * a.ld2 + (k - a.k1)];
}
__device__ __forceinline__ int regionOf(const ASrc& a, int k) {
  return k < a.k0 ? 0 : (k < a.k1 ? 1 : 2);
}

// A-staging helper: fills asb[64][72] bf16 for K-chunk kc.
template <int ABF>
__device__ __forceinline__ void stageA(
    const ASrc& A, const unsigned short* __restrict__ Abf, int lda,
    unsigned short* asb, int m0, int kc, int M, int K, int tid) {
  int row = tid & 63, kq = tid >> 6;
  int gm = m0 + row;
  if (ABF) {
    const unsigned short* rp = Abf + (size_t)gm * lda + kc + kq * 16;
    ushort4 z = make_ushort4(0, 0, 0, 0);
#pragma unroll
    for (int q = 0; q < 4; q++) {
      ushort4 v = (gm < M) ? *(const ushort4*)(rp + q * 4) : z;
      *(ushort4*)&asb[row * 72 + kq * 16 + q * 4] = v;
    }
  } else {
    bool fastc = (kc + 64 <= K) && (regionOf(A, kc) == regionOf(A, kc + 63)) &&
                 (gm < M);
    if (fastc) {
      int r = regionOf(A, kc);
      const float* p;
      int ld, koff;
      if (r == 0) { p = A.p0; ld = A.ld0; koff = 0; }
      else if (r == 1) { p = A.p1; ld = A.ld1; koff = A.k0; }
      else { p = A.p2; ld = A.ld2; koff = A.k1; }
      const float* rp = p + (size_t)gm * ld + (kc - koff) + kq * 16;
#pragma unroll
      for (int q = 0; q < 4; q++) {
        float4 v = *(const float4*)(rp + q * 4);
        *(ushort4*)&asb[row * 72 + kq * 16 + q * 4] =
            make_ushort4(f2bf(v.x), f2bf(v.y), f2bf(v.z), f2bf(v.w));
      }
    } else {
#pragma unroll
      for (int q = 0; q < 16; q++) {
        int kk = kc + kq * 16 + q;
        float v = (gm < M && kk < K) ? loadA(A, gm, kk) : 0.f;
        asb[row * 72 + kq * 16 + q] = f2bf(v);
      }
    }
  }
}

// ---------------------------------------------------------------------------
// MFMA GEMM: C[M, n0..n0+128) = act(A[M,K] @ B + bias). 64x128 tile, 4 waves.
// ---------------------------------------------------------------------------
template <int ACT, int OBF, int ABF>
__global__ __launch_bounds__(256) void gemm_mfma(
    ASrc A, const unsigned short* __restrict__ Abf, int lda,
    const unsigned short* __restrict__ Bt, int ldbt,
    const float* __restrict__ bias, void* __restrict__ Cv, int ldc, int M, int K) {
  __shared__ __align__(16) unsigned short asb[64 * 72];
  __shared__ __align__(16) unsigned short bsb[128 * 72];
  int tid = threadIdx.x;
  int m0 = blockIdx.x * 64, n0 = blockIdx.y * 128;
  int lane = tid & 63, wave = tid >> 6;
  int quad = lane >> 4, l16 = lane & 15;
  ffrag zero = {0.f, 0.f, 0.f, 0.f};
  ffrag acc[8];
#pragma unroll
  for (int t = 0; t < 8; t++) acc[t] = zero;
  int KC = (K + 63) & ~63;
  for (int kc = 0; kc < KC; kc += 64) {
    __syncthreads();
    stageA<ABF>(A, Abf, lda, asb, m0, kc, M, K, tid);
    {  // stage B chunk
      int n = tid >> 1, hf = tid & 1;
      const ushort4* rp = (const ushort4*)(Bt + (size_t)(n0 + n) * ldbt + kc + hf * 32);
      ushort4* dp = (ushort4*)&bsb[n * 72 + hf * 32];
#pragma unroll
      for (int i = 0; i < 8; i++) dp[i] = rp[i];
    }
    __syncthreads();
    int arow = wave * 16 + l16;
    bfrag a0 = *(const bfrag*)&asb[arow * 72 + quad * 8];
    bfrag a1 = *(const bfrag*)&asb[arow * 72 + 32 + quad * 8];
#pragma unroll
    for (int t = 0; t < 8; t++) {
      int bn = t * 16 + l16;
      bfrag b0 = *(const bfrag*)&bsb[bn * 72 + quad * 8];
      bfrag b1 = *(const bfrag*)&bsb[bn * 72 + 32 + quad * 8];
      acc[t] = __builtin_amdgcn_mfma_f32_16x16x32_bf16(a0, b0, acc[t], 0, 0, 0);
      acc[t] = __builtin_amdgcn_mfma_f32_16x16x32_bf16(a1, b1, acc[t], 0, 0, 0);
    }
  }
#pragma unroll
  for (int t = 0; t < 8; t++) {
    int col = n0 + t * 16 + l16;
    float bv = bias ? bias[col] : 0.f;
#pragma unroll
    for (int r = 0; r < 4; r++) {
      int row = m0 + wave * 16 + quad * 4 + r;
      if (row < M) {
        float v = acc[t][r] + bv;
        if (ACT == 1) v = fmaxf(v, 0.f);
        if (OBF)
          ((unsigned short*)Cv)[(size_t)row * ldc + col] = f2bf(v);
        else
          ((float*)Cv)[(size_t)row * ldc + col] = v;
      }
    }
  }
}

// ---------------------------------------------------------------------------
// Dual-B MFMA GEMM: stages A once per K-chunk, accumulates A@B1 and A@B2.
// ---------------------------------------------------------------------------
template <int OBF, int ABF>
__global__ __launch_bounds__(256) void gemm_dual(
    ASrc A, const unsigned short* __restrict__ Abf, int lda,
    const unsigned short* __restrict__ Bt1, const unsigned short* __restrict__ Bt2,
    int ldbt, void* __restrict__ Cv1, void* __restrict__ Cv2, int ldc,
    int M, int K) {
  __shared__ __align__(16) unsigned short asb[64 * 72];
  __shared__ __align__(16) unsigned short bsb[128 * 72];
  int tid = threadIdx.x;
  int m0 = blockIdx.x * 64, n0 = blockIdx.y * 128;
  int lane = tid & 63, wave = tid >> 6;
  int quad = lane >> 4, l16 = lane & 15;
  ffrag zero = {0.f, 0.f, 0.f, 0.f};
  ffrag acc1[8], acc2[8];
#pragma unroll
  for (int t = 0; t < 8; t++) { acc1[t] = zero; acc2[t] = zero; }
  int KC = (K + 63) & ~63;
  int arow = wave * 16 + l16;
  for (int kc = 0; kc < KC; kc += 64) {
    __syncthreads();
    stageA<ABF>(A, Abf, lda, asb, m0, kc, M, K, tid);
    {  // stage B1 chunk
      int n = tid >> 1, hf = tid & 1;
      const ushort4* rp = (const ushort4*)(Bt1 + (size_t)(n0 + n) * ldbt + kc + hf * 32);
      ushort4* dp = (ushort4*)&bsb[n * 72 + hf * 32];
#pragma unroll
      for (int i = 0; i < 8; i++) dp[i] = rp[i];
    }
    __syncthreads();
    bfrag a0 = *(const bfrag*)&asb[arow * 72 + quad * 8];
    bfrag a1 = *(const bfrag*)&asb[arow * 72 + 32 + quad * 8];
#pragma unroll
    for (int t = 0; t < 8; t++) {
      int bn = t * 16 + l16;
      bfrag b0 = *(const bfrag*)&bsb[bn * 72 + quad * 8];
      bfrag b1 = *(const bfrag*)&bsb[bn * 72 + 32 + quad * 8];
      acc1[t] = __builtin_amdgcn_mfma_f32_16x16x32_bf16(a0, b0, acc1[t], 0, 0, 0);
      acc1[t] = __builtin_amdgcn_mfma_f32_16x16x32_bf16(a1, b1, acc1[t], 0, 0, 0);
    }
    __syncthreads();  // B1 reads complete before restage
    {  // stage B2 chunk
      int n = tid >> 1, hf = tid & 1;
      const ushort4* rp = (const ushort4*)(Bt2 + (size_t)(n0 + n) * ldbt + kc + hf * 32);
      ushort4* dp = (ushort4*)&bsb[n * 72 + hf * 32];
#pragma unroll
      for (int i = 0; i < 8; i++) dp[i] = rp[i];
    }
    __syncthreads();
#pragma unroll
    for (int t = 0; t < 8; t++) {
      int bn = t * 16 + l16;
      bfrag b0 = *(const bfrag*)&bsb[bn * 72 + quad * 8];
      bfrag b1 = *(const bfrag*)&bsb[bn * 72 + 32 + quad * 8];
      acc2[t] = __builtin_amdgcn_mfma_f32_16x16x32_bf16(a0, b0, acc2[t], 0, 0, 0);
      acc2[t] = __builtin_amdgcn_mfma_f32_16x16x32_bf16(a1, b1, acc2[t], 0, 0, 0);
    }
  }
#pragma unroll
  for (int t = 0; t < 8; t++) {
    int col = n0 + t * 16 + l16;
#pragma unroll
    for (int r = 0; r < 4; r++) {
      int row = m0 + wave * 16 + quad * 4 + r;
      if (row < M) {
        if (OBF) {
          ((unsigned short*)Cv1)[(size_t)row * ldc + col] = f2bf(acc1[t][r]);
          ((unsigned short*)Cv2)[(size_t)row * ldc + col] = f2bf(acc2[t][r]);
        } else {
          ((float*)Cv1)[(size_t)row * ldc + col] = acc1[t][r];
          ((float*)Cv2)[(size_t)row * ldc + col] = acc2[t][r];
        }
      }
    }
  }
}

// ---------------------------------------------------------------------------
// gather-mean, 8B-vectorized: 2 edges per wave iteration, shfl_xor(32) combine.
// ---------------------------------------------------------------------------
__global__ __launch_bounds__(256) void gather_mean(
    const int* __restrict__ row_src, const int* __restrict__ eid_src,
    const int* __restrict__ row_ext, const int* __restrict__ ext_eid,
    const unsigned short* __restrict__ emb, const unsigned short* __restrict__ eab,
    float* __restrict__ xout, float* __restrict__ xin,
    unsigned short* __restrict__ lattrb, int N) {
  int lane = threadIdx.x & 63, wid = threadIdx.x >> 6;
  int n = blockIdx.x * 4 + wid;
  int side = blockIdx.y;
  if (n >= N) return;
  int lo, hi;
  const int* eid;
  if (side) { lo = row_ext[n]; hi = row_ext[n + 1] - 1; eid = ext_eid; }
  else { lo = row_src[n]; hi = row_src[n + 1]; eid = eid_src; }
  int half = lane >> 5;
  int l32 = lane & 31;
  int c4 = l32 * 4;
  float a0 = 0.f, a1 = 0.f, a2 = 0.f, a3 = 0.f;
  float la0 = 0.f, la1 = 0.f;
  int j = lo;
  for (; j + 1 < hi; j += 2) {
    int e = eid[j + half];
    ushort4 v = *(const ushort4*)&emb[(size_t)e * 128 + c4];
    a0 += bf2f(v.x); a1 += bf2f(v.y); a2 += bf2f(v.z); a3 += bf2f(v.w);
    if (side) {
      ushort2 u = *(const ushort2*)&eab[(size_t)e * 64 + l32 * 2];
      la0 += bf2f(u.x); la1 += bf2f(u.y);
    }
  }
  if (j < hi && half == 0) {  // odd tail: lanes 0-31 only
    int e = eid[j];
    ushort4 v = *(const ushort4*)&emb[(size_t)e * 128 + c4];
    a0 += bf2f(v.x); a1 += bf2f(v.y); a2 += bf2f(v.z); a3 += bf2f(v.w);
    if (side) {
      ushort2 u = *(const ushort2*)&eab[(size_t)e * 64 + l32 * 2];
      la0 += bf2f(u.x); la1 += bf2f(u.y);
    }
  }
  a0 += __shfl_xor(a0, 32);
  a1 += __shfl_xor(a1, 32);
  a2 += __shfl_xor(a2, 32);
  a3 += __shfl_xor(a3, 32);
  if (side) {
    la0 += __shfl_xor(la0, 32);
    la1 += __shfl_xor(la1, 32);
  }
  float r = 1.f / fmaxf((float)(hi - lo), 1.f);
  if (half == 0) {
    float* ob = side ? xin : xout;
    *(float4*)&ob[(size_t)n * 128 + c4] =
        make_float4(a0 * r, a1 * r, a2 * r, a3 * r);
    if (side)
      *(ushort2*)&lattrb[(size_t)n * 64 + l32 * 2] =
          make_ushort2(f2bf(la0 * r), f2bf(la1 * r));
  }
}

// ---------------------------------------------------------------------------
// attn_logits_mfma<H> — dst-sorted edges; stores a = exp(min(logit,60)) at
// sorted position j. ssrc/sdst give sequential index reads.
// ---------------------------------------------------------------------------
template <int H>
__global__ __launch_bounds__(256) void attn_logits_mfma(
    const unsigned short* __restrict__ xl, const unsigned short* __restrict__ xr,
    const int* __restrict__ ssrc, const int* __restrict__ sdst,
    const unsigned short* __restrict__ eab, const unsigned short* __restrict__ lattrb,
    const int* __restrict__ ext_eid,
    const unsigned short* __restrict__ wet, const float* __restrict__ att,
    float* __restrict__ lg, int E, int N) {
  constexpr int HC = H * 128;
  __shared__ __align__(16) unsigned short asb[64 * 72];
  __shared__ __align__(16) unsigned short bsb[128 * 72];  // reused as Cs[64][136]
  __shared__ float atts[128];
  __shared__ int sidx[64], didx[64];
  unsigned short* Cs = bsb;
  int tid = threadIdx.x;
  int E2 = E + N;
  int i0 = blockIdx.x * 64;
  int lane = tid & 63, wave = tid >> 6, quad = lane >> 4, l16 = lane & 15;
  if (tid < 64) {
    int j = i0 + tid;
    sidx[tid] = (j < E2) ? ssrc[j] : 0;
    didx[tid] = (j < E2) ? sdst[j] : 0;
  }
  {  // stage A once (bf16 sources, dst-sorted edge order)
    int row = tid & 63, kq = tid >> 6;
    int j = i0 + row;
    if (j < E2) {
      int e = ext_eid[j];
      const unsigned short* ap =
          (e < E) ? eab + (size_t)e * 64 : lattrb + (size_t)(e - E) * 64;
      const ushort4* rp = (const ushort4*)(ap + kq * 16);
#pragma unroll
      for (int q = 0; q < 4; q++)
        *(ushort4*)&asb[row * 72 + kq * 16 + q * 4] = rp[q];
    } else {
      ushort4 z = make_ushort4(0, 0, 0, 0);
#pragma unroll
      for (int q = 0; q < 4; q++) *(ushort4*)&asb[row * 72 + kq * 16 + q * 4] = z;
    }
  }
  int er = tid >> 4, cc = tid & 15;
  ffrag zero = {0.f, 0.f, 0.f, 0.f};
  for (int head = 0; head < H; head++) {
    int n0 = head * 128;
    __syncthreads();
    if (tid < 128) atts[tid] = att[n0 + tid];
    {
      int n = tid >> 1, hf = tid & 1;
      const ushort4* rp = (const ushort4*)(wet + (size_t)(n0 + n) * 64 + hf * 32);
      ushort4* dp = (ushort4*)&bsb[n * 72 + hf * 32];
#pragma unroll
      for (int i = 0; i < 8; i++) dp[i] = rp[i];
    }
    __syncthreads();
    int arow = wave * 16 + l16;
    bfrag a0 = *(const bfrag*)&asb[arow * 72 + quad * 8];
    bfrag a1 = *(const bfrag*)&asb[arow * 72 + 32 + quad * 8];
    ffrag acc[8];
#pragma unroll
    for (int t = 0; t < 8; t++) {
      acc[t] = zero;
      int bn = t * 16 + l16;
      bfrag b0 = *(const bfrag*)&bsb[bn * 72 + quad * 8];
      bfrag b1 = *(const bfrag*)&bsb[bn * 72 + 32 + quad * 8];
      acc[t] = __builtin_amdgcn_mfma_f32_16x16x32_bf16(a0, b0, acc[t], 0, 0, 0);
      acc[t] = __builtin_amdgcn_mfma_f32_16x16x32_bf16(a1, b1, acc[t], 0, 0, 0);
    }
    __syncthreads();
    {
      int rb = wave * 16 + quad * 4;
#pragma unroll
      for (int t = 0; t < 8; t++)
#pragma unroll
        for (int r = 0; r < 4; r++)
          Cs[(rb + r) * 136 + t * 16 + l16] = f2bf(acc[t][r]);
    }
    __syncthreads();
#pragma unroll
    for (int i2 = 0; i2 < 4; i2++) {
      int r = er * 4 + i2;
      int gi = i0 + r;
      float ps = 0.f;
      if (gi < E2) {
        int s = sidx[r], d = didx[r];
#pragma unroll
        for (int h = 0; h < 2; h++) {
          int c = h * 64 + cc * 4;
          ushort4 mv = *(const ushort4*)&Cs[r * 136 + c];
          ushort4 xlu = *(const ushort4*)&xl[(size_t)s * HC + n0 + c];
          ushort4 xru = *(const ushort4*)&xr[(size_t)d * HC + n0 + c];
          float e0 = bf2f(mv.x) + bf2f(xlu.x) + bf2f(xru.x);
          float e1 = bf2f(mv.y) + bf2f(xlu.y) + bf2f(xru.y);
          float e2 = bf2f(mv.z) + bf2f(xlu.z) + bf2f(xru.z);
          float e3 = bf2f(mv.w) + bf2f(xlu.w) + bf2f(xru.w);
          e0 = e0 > 0.f ? e0 : 0.2f * e0;
          e1 = e1 > 0.f ? e1 : 0.2f * e1;
          e2 = e2 > 0.f ? e2 : 0.2f * e2;
          e3 = e3 > 0.f ? e3 : 0.2f * e3;
          ps += e0 * atts[c + 0] + e1 * atts[c + 1] + e2 * atts[c + 2] +
                e3 * atts[c + 3];
        }
      }
      ps += __shfl_xor(ps, 1);
      ps += __shfl_xor(ps, 2);
      ps += __shfl_xor(ps, 4);
      ps += __shfl_xor(ps, 8);
      if (cc == 0 && gi < E2)
        lg[(size_t)gi * H + head] = __expf(fminf(ps, 60.f));
    }
  }
}

// ---------------------------------------------------------------------------
// attn_fused<H> — lg holds pre-exponentiated a at sorted position j; ssrc
// gives the source node sequentially (no dependent random index load).
// ---------------------------------------------------------------------------
template <int H>
__global__ __launch_bounds__(256) void attn_fused(
    const unsigned short* __restrict__ xl, const float* __restrict__ lg,
    const int* __restrict__ row_ext, const int* __restrict__ ssrc,
    const float* __restrict__ bias,
    const float* __restrict__ gam, const float* __restrict__ bet,
    unsigned short* __restrict__ hout, int E, int N) {
  constexpr int HC = H * 128;
  constexpr int CPL = HC / 64;
  int lane = threadIdx.x & 63, wid = threadIdx.x >> 6;
  int n = blockIdx.x * 4 + wid;
  if (n >= N) return;
  int lo = row_ext[n], hi = row_ext[n + 1];
  int myh = (H == 2) ? (lane >> 5) : 0;
  int colbase = (H == 2) ? (myh * 128 + (lane & 31) * 4) : (lane * 2);
  float asum = 0.f;
  float acc[CPL] = {};
  for (int j = lo; j < hi; j++) {
    int s = ssrc[j];
    float a = lg[(size_t)j * H + myh];
    asum += a;
    const unsigned short* xp = &xl[(size_t)s * HC + colbase];
    if (H == 2) {
      ushort4 u = *(const ushort4*)xp;
      acc[0] += a * bf2f(u.x);
      acc[1] += a * bf2f(u.y);
      acc[2] += a * bf2f(u.z);
      acc[3] += a * bf2f(u.w);
    } else {
      ushort2 u = *(const ushort2*)xp;
      acc[0] += a * bf2f(u.x);
      acc[1] += a * bf2f(u.y);
    }
  }
  float inv = 1.f / fmaxf(asum, 1e-16f);
#pragma unroll
  for (int k = 0; k < CPL; k++) acc[k] *= inv;
  int ch;
  if (H == 2) {
#pragma unroll
    for (int k = 0; k < CPL; k++) acc[k] = (acc[k] + __shfl_xor(acc[k], 32)) * 0.5f;
    ch = (lane & 31) * CPL;
  } else {
    ch = lane * CPL;
  }
#pragma unroll
  for (int k = 0; k < CPL; k++) acc[k] += bias[ch + k];
  float s = 0.f;
#pragma unroll
  for (int k = 0; k < CPL; k++) s += acc[k];
#pragma unroll
  for (int mm = 1; mm < 64; mm <<= 1) s += __shfl_xor(s, mm);
  constexpr float dupn = (H == 2) ? 256.f : 128.f;
  float mu = s / dupn;
  float vs = 0.f;
#pragma unroll
  for (int k = 0; k < CPL; k++) {
    acc[k] -= mu;
    vs += acc[k] * acc[k];
  }
#pragma unroll
  for (int mm = 1; mm < 64; mm <<= 1) vs += __shfl_xor(vs, mm);
  float rstd = rsqrtf(vs / dupn + 1e-5f);
  float y[CPL];
#pragma unroll
  for (int k = 0; k < CPL; k++) {
    float v = acc[k] * rstd * gam[ch + k] + bet[ch + k];
    y[k] = v > 0.f ? v : expm1f(v);
  }
  if (H == 2) {
    if (lane < 32)
      *(ushort4*)&hout[(size_t)n * 128 + ch] =
          make_ushort4(f2bf(y[0]), f2bf(y[1]), f2bf(y[2]), f2bf(y[3]));
  } else {
    *(ushort2*)&hout[(size_t)n * 128 + ch] = make_ushort2(f2bf(y[0]), f2bf(y[1]));
  }
}

// ---------------------------------------------------------------------------
// classifier_mfma — fully fused (round-14 staging) + LDS union arena:
// {asb,bsb} (MFMA phases) alias {t1s,c2s} (epilogue) => ~37KB LDS, 4 blk/CU.
// c1 = ea@c1wc + h2[s]@c1wa + h2[d]@c1wb (fp32 MFMA accumulation), then
// relu -> c2 -> relu -> c3. src-sorted edges; out scattered via eidx.
// ---------------------------------------------------------------------------
__global__ __launch_bounds__(256) void classifier_mfma(
    const unsigned short* __restrict__ eab, const unsigned short* __restrict__ h2b,
    const int* __restrict__ eid_src,
    const int* __restrict__ src, const int* __restrict__ dst,
    const unsigned short* __restrict__ c1wct, const unsigned short* __restrict__ c1wat,
    const unsigned short* __restrict__ c1wbt,
    const float* __restrict__ c1b, const unsigned short* __restrict__ c2t,
    const float* __restrict__ c2b, const float* __restrict__ c3w,
    const float* __restrict__ c3b, float* __restrict__ out, int E) {
  // union arena: phases use asb[64*72] + bsb[128*72] = 27648B;
  // epilogue uses t1s[64*136] + c2s[64*136] = 34816B. Peak 34816B.
  __shared__ __align__(16) unsigned char arena[34816];
  unsigned short* asb = (unsigned short*)arena;             // [64*72]
  unsigned short* bsb = (unsigned short*)(arena + 9216);    // [128*72]
  unsigned short* t1s = (unsigned short*)arena;             // [64*136]
  unsigned short* c2s = (unsigned short*)(arena + 17408);   // [64*136]
  __shared__ float c1bs[128];
  __shared__ float c2bs[64], c3ws[64];
  __shared__ int sidx[64], didx[64], eidx[64];
  int tid = threadIdx.x;
  int e0 = blockIdx.x * 64;
  int lane = tid & 63, wave = tid >> 6, quad = lane >> 4, l16 = lane & 15;
  if (tid < 128) c1bs[tid] = c1b[tid];
  if (tid < 64) {
    c2bs[tid] = c2b[tid];
    c3ws[tid] = c3w[tid];
    int j = e0 + tid;
    int e = (j < E) ? eid_src[j] : -1;
    eidx[tid] = e;
    sidx[tid] = (e >= 0) ? src[e] : 0;
    didx[tid] = (e >= 0) ? dst[e] : 0;
  }
  ffrag zero = {0.f, 0.f, 0.f, 0.f};
  ffrag acc[8];
#pragma unroll
  for (int t = 0; t < 8; t++) acc[t] = zero;
  int arow = wave * 16 + l16;
  // ---- phase 1: ea @ c1wc (K=64) ----
  {
    int row = tid & 63, kq = tid >> 6;
    int j = e0 + row;
    if (j < E) {
      int e = eid_src[j];
      const ushort4* rp = (const ushort4*)(eab + (size_t)e * 64 + kq * 16);
#pragma unroll
      for (int q = 0; q < 4; q++)
        *(ushort4*)&asb[row * 72 + kq * 16 + q * 4] = rp[q];
    } else {
      ushort4 z = make_ushort4(0, 0, 0, 0);
#pragma unroll
      for (int q = 0; q < 4; q++) *(ushort4*)&asb[row * 72 + kq * 16 + q * 4] = z;
    }
    int n = tid >> 1, hf = tid & 1;
    const ushort4* rp2 = (const ushort4*)(c1wct + (size_t)n * 64 + hf * 32);
    ushort4* dp = (ushort4*)&bsb[n * 72 + hf * 32];
#pragma unroll
    for (int i = 0; i < 8; i++) dp[i] = rp2[i];
  }
  __syncthreads();
  {
    bfrag a0 = *(const bfrag*)&asb[arow * 72 + quad * 8];
    bfrag a1 = *(const bfrag*)&asb[arow * 72 + 32 + quad * 8];
#pragma unroll
    for (int t = 0; t < 8; t++) {
      int bn = t * 16 + l16;
      bfrag b0 = *(const bfrag*)&bsb[bn * 72 + quad * 8];
      bfrag b1 = *(const bfrag*)&bsb[bn * 72 + 32 + quad * 8];
      acc[t] = __builtin_amdgcn_mfma_f32_16x16x32_bf16(a0, b0, acc[t], 0, 0, 0);
      acc[t] = __builtin_amdgcn_mfma_f32_16x16x32_bf16(a1, b1, acc[t], 0, 0, 0);
    }
  }
  // ---- phases 2,3: h2[s]@c1wa, h2[d]@c1wb — K=128, staged in 64-col halves ----
  for (int ph = 0; ph < 2; ph++) {
    const int* idx = ph ? didx : sidx;
    const unsigned short* Wt = ph ? c1wbt : c1wat;
#pragma unroll
    for (int kc = 0; kc < 2; kc++) {
      __syncthreads();  // prior MFMA reads of asb/bsb complete
      {  // stage A half: h2[idx][kc*64 .. +64)  (128B gather per row)
        int row = tid & 63, kq = tid >> 6;
        int s = idx[row];
        const ushort4* rp =
            (const ushort4*)(h2b + (size_t)s * 128 + kc * 64 + kq * 16);
#pragma unroll
        for (int q = 0; q < 4; q++)
          *(ushort4*)&asb[row * 72 + kq * 16 + q * 4] = rp[q];
        // stage B half: Wt[n][kc*64 .. +64)
        int n = tid >> 1, hf = tid & 1;
        const ushort4* rp2 =
            (const ushort4*)(Wt + (size_t)n * 128 + kc * 64 + hf * 32);
        ushort4* dp = (ushort4*)&bsb[n * 72 + hf * 32];
#pragma unroll
        for (int i = 0; i < 8; i++) dp[i] = rp2[i];
      }
      __syncthreads();
      bfrag a0 = *(const bfrag*)&asb[arow * 72 + quad * 8];
      bfrag a1 = *(const bfrag*)&asb[arow * 72 + 32 + quad * 8];
#pragma unroll
      for (int t = 0; t < 8; t++) {
        int bn = t * 16 + l16;
        bfrag b0 = *(const bfrag*)&bsb[bn * 72 + quad * 8];
        bfrag b1 = *(const bfrag*)&bsb[bn * 72 + 32 + quad * 8];
        acc[t] = __builtin_amdgcn_mfma_f32_16x16x32_bf16(a0, b0, acc[t], 0, 0, 0);
        acc[t] = __builtin_amdgcn_mfma_f32_16x16x32_bf16(a1, b1, acc[t], 0, 0, 0);
      }
    }
  }
  __syncthreads();  // phase reads done; arena is repartitioned as t1s/c2s
  // ---- c1 epilogue -> t1s bf16; stage c2t into c2s ----
  {
    int rb = wave * 16 + quad * 4;
#pragma unroll
    for (int t = 0; t < 8; t++) {
      int col = t * 16 + l16;
#pragma unroll
      for (int r = 0; r < 4; r++) {
        float v = acc[t][r] + c1bs[col];
        t1s[(rb + r) * 136 + col] = f2bf(fmaxf(v, 0.f));
      }
    }
    int n = tid >> 2, qq = tid & 3;
    const ushort4* rp = (const ushort4*)(c2t + (size_t)n * 128 + qq * 32);
    ushort4* dp = (ushort4*)&c2s[n * 136 + qq * 32];
#pragma unroll
    for (int i = 0; i < 8; i++) dp[i] = rp[i];
  }
  __syncthreads();
  {
    bfrag pa[4];
#pragma unroll
    for (int kc = 0; kc < 4; kc++)
      pa[kc] = *(const bfrag*)&t1s[arow * 136 + kc * 32 + quad * 8];
    ffrag acc2[4];
#pragma unroll
    for (int t = 0; t < 4; t++) {
      acc2[t] = zero;
      int bn = t * 16 + l16;
#pragma unroll
      for (int kc = 0; kc < 4; kc++) {
        bfrag b = *(const bfrag*)&c2s[bn * 136 + kc * 32 + quad * 8];
        acc2[t] = __builtin_amdgcn_mfma_f32_16x16x32_bf16(pa[kc], b, acc2[t], 0, 0, 0);
      }
    }
    float c3b0 = c3b[0];
    float rsum[4] = {0.f, 0.f, 0.f, 0.f};
#pragma unroll
    for (int t = 0; t < 4; t++) {
      int col = t * 16 + l16;
      float cb = c2bs[col], cw = c3ws[col];
#pragma unroll
      for (int r = 0; r < 4; r++)
        rsum[r] += fmaxf(acc2[t][r] + cb, 0.f) * cw;
    }
#pragma unroll
    for (int r = 0; r < 4; r++) {
      rsum[r] += __shfl_xor(rsum[r], 1);
      rsum[r] += __shfl_xor(rsum[r], 2);
      rsum[r] += __shfl_xor(rsum[r], 4);
      rsum[r] += __shfl_xor(rsum[r], 8);
    }
    if (l16 == 0) {
#pragma unroll
      for (int r = 0; r < 4; r++) {
        int e = eidx[wave * 16 + quad * 4 + r];
        if (e >= 0) out[e] = rsum[r] + c3b0;
      }
    }
  }
}

// ---------------------------------------------------------------------------
extern "C" void kernel_launch(void* const* d_in, const int* in_sizes, int n_in,
                              void* d_out, int out_size, void* d_ws, size_t ws_size,
                              hipStream_t stream) {
  const int N = in_sizes[1] / 2;   // node_stats [N,2]
  const int E = in_sizes[3] / 64;  // edge_attr [E,64]
  const int E2 = E + N;
  const int nb = cdiv(N, 256);     // scan blocks per array (<=1024)

  const float* node_stats = (const float*)d_in[1];
  const int* src = (const int*)d_in[2];
  const int* dst = (const int*)d_in[2] + E;
  const float* edge_attr = (const float*)d_in[3];
  const float* epw = (const float*)d_in[4];
  const float* epb = (const float*)d_in[5];
  const float* g1wl = (const float*)d_in[6];
  const float* g1wr = (const float*)d_in[7];
  const float* g1we = (const float*)d_in[8];
  const float* g1att = (const float*)d_in[9];
  const float* g1b = (const float*)d_in[10];
  const float* n1g = (const float*)d_in[11];
  const float* n1b = (const float*)d_in[12];
  const float* g2wl = (const float*)d_in[13];
  const float* g2wr = (const float*)d_in[14];
  const float* g2we = (const float*)d_in[15];
  const float* g2att = (const float*)d_in[16];
  const float* g2b = (const float*)d_in[17];
  const float* n2g = (const float*)d_in[18];
  const float* n2b = (const float*)d_in[19];
  const float* c1w = (const float*)d_in[20];
  const float* c1b = (const float*)d_in[21];
  const float* c2w = (const float*)d_in[22];
  const float* c2b = (const float*)d_in[23];
  const float* c3w = (const float*)d_in[24];
  const float* c3b = (const float*)d_in[25];
  float* out = (float*)d_out;

  // workspace arena (float units)
  float* w = (float*)d_ws;
  size_t o = 0;
  auto alloc = [&](size_t n) { float* p = w + o; o += n; return p; };
  float* xout = alloc((size_t)N * 128);
  float* xin = alloc((size_t)N * 128);
  float* lattr = alloc((size_t)N * 64);  // used as bf16 [N][64]
  float* lg = alloc((size_t)E2 * 2);
  int* row_src = (int*)alloc((size_t)(N + 1));
  int* row_dst = (int*)alloc((size_t)(N + 1));
  int* row_ext = (int*)alloc((size_t)(N + 1));
  int* deg_src = (int*)alloc((size_t)N);  // deg pair contiguous (memset)
  int* deg_dst = (int*)alloc((size_t)N);
  int* cur_src = (int*)alloc((size_t)N);
  int* cur_ext = (int*)alloc((size_t)N);
  int* eid_src = (int*)alloc((size_t)E);
  int* ext_eid = (int*)alloc((size_t)E2);
  int* ssrc = (int*)alloc((size_t)E2);
  int* sdst = (int*)alloc((size_t)E2);
  int* bsum = (int*)alloc((size_t)2 * 1024);
  unsigned short* wb = (unsigned short*)alloc(140000);  // bf16 weight arena
  unsigned short* eab = (unsigned short*)alloc((size_t)E * 32);  // edge_attr bf16
  float* R = alloc((size_t)E * 64);  // bf16 feature arena (E*128 ushorts)
  unsigned short* Ru = (unsigned short*)R;
  unsigned short* emb = Ru;                                // E*128
  unsigned short* xl1b = Ru;                               // N*256 (emb dead)
  unsigned short* xr1b = Ru + (size_t)N * 256;             // N*256
  unsigned short* h1b = Ru + (size_t)N * 512;              // N*128
  unsigned short* xl2b = Ru + (size_t)N * 640;             // N*128
  unsigned short* xr2b = Ru + (size_t)N * 768;             // N*128
  unsigned short* h2b = Ru + (size_t)N * 896;              // N*128
  unsigned short* lattrb = (unsigned short*)lattr;

  // bf16 transposed weights
  unsigned short* epwt = wb + 0;        // [128][64]
  unsigned short* g1wlt = wb + 8192;    // [256][320]
  unsigned short* g1wrt = wb + 90112;   // [256][320]
  unsigned short* g1wet = wb + 172032;  // [256][64]
  unsigned short* g2wlt = wb + 188416;  // [128][128]
  unsigned short* g2wrt = wb + 204800;  // [128][128]
  unsigned short* g2wet = wb + 221184;  // [128][64]
  unsigned short* c1wat = wb + 229376;  // [128][128]
  unsigned short* c1wbt = wb + 245760;  // [128][128]
  unsigned short* c1wct = wb + 262144;  // [128][64]
  unsigned short* c2t = wb + 270336;    // [64][128]

  // ---- stage -1: weight prep + bf16 edge_attr ----
  cvt_bf16<<<2048, 256, 0, stream>>>(edge_attr, eab, E * 16);
  PrepJobs J;
  auto setj = [&](int i, const float* s, unsigned short* d2, int K, int Nc,
                  int KC, int ld) {
    J.src[i] = s; J.dst[i] = d2; J.K[i] = K; J.Nc[i] = Nc; J.KC[i] = KC; J.ld[i] = ld;
  };
  setj(0, epw, epwt, 64, 128, 64, 128);
  setj(1, g1wl, g1wlt, 258, 256, 320, 256);
  setj(2, g1wr, g1wrt, 258, 256, 320, 256);
  setj(3, g1we, g1wet, 64, 256, 64, 256);
  setj(4, g2wl, g2wlt, 128, 128, 128, 128);
  setj(5, g2wr, g2wrt, 128, 128, 128, 128);
  setj(6, g2we, g2wet, 64, 128, 64, 128);
  setj(7, c1w, c1wat, 128, 128, 128, 128);
  setj(8, c1w + 128 * 128, c1wbt, 128, 128, 128, 128);
  setj(9, c1w + 256 * 128, c1wct, 64, 128, 64, 128);
  setj(10, c2w, c2t, 128, 64, 128, 64);
  prep_bt<<<dim3(11, 32), 256, 0, stream>>>(J);

  // ---- stage 0: CSR (src) + extended dst CSR (parallel scan) ----
  hipMemsetAsync(deg_src, 0, (size_t)2 * N * sizeof(int), stream);
  count_deg<<<cdiv(E, 256), 256, 0, stream>>>(src, dst, deg_src, deg_dst, E);
  scan_local<<<dim3(nb, 2), 256, 0, stream>>>(deg_src, deg_dst, row_src, row_dst,
                                              bsum, N, nb);
  scan_bsums<<<1, 1024, 0, stream>>>(bsum, nb, row_src, row_dst, N);
  scan_add<<<dim3(nb, 2), 256, 0, stream>>>(row_src, row_dst, cur_src, bsum, N, nb);
  ext_fix<<<cdiv(N + 1, 256), 256, 0, stream>>>(row_dst, row_ext, cur_ext,
                                                ext_eid, ssrc, sdst, E, N);
  scatter_eid<<<cdiv(E, 256), 256, 0, stream>>>(src, dst, cur_src, cur_ext,
                                                eid_src, ext_eid, ssrc, sdst, E);

  ASrc dummy{nullptr, nullptr, nullptr, 0, 0, 0, 0, 0};

  // ---- stage 1: emb = relu(ea@epw+epb) bf16; gather means ----
  gemm_mfma<1, 1, 1><<<dim3(cdiv(E, 64), 1), 256, 0, stream>>>(
      dummy, eab, 64, epwt, 64, epb, emb, 128, E, 64);
  gather_mean<<<dim3(cdiv(N, 4), 2), 256, 0, stream>>>(
      row_src, eid_src, row_ext, ext_eid, emb, eab, xout, xin, lattrb, N);

  // ---- stage 2: xl1/xr1 (bf16) = xi @ g1wl / g1wr — dual-B, A staged once ----
  {
    ASrc a{xout, xin, node_stats, 128, 128, 2, 128, 256};
    dim3 g(cdiv(N, 64), 2);
    gemm_dual<1, 0><<<g, 256, 0, stream>>>(a, nullptr, 0, g1wlt, g1wrt, 320,
                                           xl1b, xr1b, 256, N, 258);
  }

  // ---- stage 3: GATv2 layer 1 (H=2) ----
  attn_logits_mfma<2><<<cdiv(E2, 64), 256, 0, stream>>>(
      xl1b, xr1b, ssrc, sdst, eab, lattrb, ext_eid, g1wet, g1att, lg, E, N);
  attn_fused<2><<<cdiv(N, 4), 256, 0, stream>>>(xl1b, lg, row_ext, ssrc,
                                                g1b, n1g, n1b, h1b, E, N);

  // ---- stage 4: xl2/xr2 (bf16) = h1 @ g2wl / g2wr — dual-B ----
  {
    dim3 g(cdiv(N, 64), 1);
    gemm_dual<1, 1><<<g, 256, 0, stream>>>(dummy, h1b, 128, g2wlt, g2wrt, 128,
                                           xl2b, xr2b, 128, N, 128);
  }

  // ---- stage 5: GATv2 layer 2 (H=1) ----
  attn_logits_mfma<1><<<cdiv(E2, 64), 256, 0, stream>>>(
      xl2b, xr2b, ssrc, sdst, eab, lattrb, ext_eid, g2wet, g2att, lg, E, N);
  attn_fused<1><<<cdiv(N, 4), 256, 0, stream>>>(xl2b, lg, row_ext, ssrc,
                                                g2b, n2g, n2b, h2b, E, N);

  // ---- stage 6: classifier, fully fused (union-arena LDS) ----
  classifier_mfma<<<cdiv(E, 64), 256, 0, stream>>>(
      eab, h2b, eid_src, src, dst, c1wct, c1wat, c1wbt, c1b, c2t, c2b, c3w,
      c3b, out, E);
}

// Round 10
// 887.010 us; speedup vs baseline: 1.0060x; 1.0006x over previous
//
#include <hip/hip_runtime.h>
#include <cstdint>
#include <cstddef>

// ---------------------------------------------------------------------------
// StaticGNN fused pipeline, round 17: round-16 (best, 887.6us) +
//  - xi stored bf16 [N][320] (x_out|x_in|node_stats|zero-pad): gather_mean
//    writes bf16 directly (bit-identical: f2bf happened in stageA anyway),
//    stage-2 gemm_dual takes the ABF fast path => A-read bytes halve and
//    per-tile f2bf VALU staging disappears.
//  - cvt_bf16 + count_deg merged into one launch.
// Classifier keeps round-16 union-arena (37KB LDS). Lessons kept: no global
// atomic scatter (r12), no register-prefetch wait-wall (r15).
// N=50000, E=400000, ND=128, ED=64, HID=128.
// ---------------------------------------------------------------------------

static inline int cdiv(int a, int b) { return (a + b - 1) / b; }

typedef __attribute__((ext_vector_type(8))) short bfrag;   // 8 bf16 (4 VGPRs)
typedef __attribute__((ext_vector_type(4))) float ffrag;   // 4 fp32 acc

__device__ __forceinline__ float bf2f(unsigned short u) {
  return __uint_as_float(((unsigned)u) << 16);
}
__device__ __forceinline__ unsigned short f2bf(float f) {
  unsigned b = __float_as_uint(f);
  return (unsigned short)((b + 0x7FFFu + ((b >> 16) & 1u)) >> 16);
}

// ---------------------------------------------------------------------------
// Weight prep: W[K][Nc] fp32 -> Wt[Nc][KC] bf16 (zero-padded K -> KC).
// ---------------------------------------------------------------------------
struct PrepJobs {
  const float* src[11];
  unsigned short* dst[11];
  int K[11], Nc[11], KC[11], ld[11];
};
__global__ void prep_bt(PrepJobs J) {
  int j = blockIdx.x;
  int K = J.K[j], Nc = J.Nc[j], KC = J.KC[j], ld = J.ld[j];
  const float* S = J.src[j];
  unsigned short* D = J.dst[j];
  for (int n = blockIdx.y; n < Nc; n += gridDim.y)
    for (int t = threadIdx.x; t < KC; t += blockDim.x) {
      float v = (t < K) ? S[(size_t)t * ld + n] : 0.f;
      D[(size_t)n * KC + t] = f2bf(v);
    }
}

// fp32 -> bf16 bulk convert (float4 -> ushort4) + degree count (merged)
__global__ __launch_bounds__(256) void cvt_cnt(const float* __restrict__ in,
                                               unsigned short* __restrict__ out,
                                               int n4,
                                               const int* __restrict__ src,
                                               const int* __restrict__ dst,
                                               int* __restrict__ dsrc,
                                               int* __restrict__ ddst, int E) {
  int stride = gridDim.x * blockDim.x;
  for (int i = blockIdx.x * blockDim.x + threadIdx.x; i < n4; i += stride) {
    float4 v = ((const float4*)in)[i];
    ((ushort4*)out)[i] = make_ushort4(f2bf(v.x), f2bf(v.y), f2bf(v.z), f2bf(v.w));
  }
  for (int t = blockIdx.x * blockDim.x + threadIdx.x; t < E; t += stride) {
    atomicAdd(&dsrc[src[t]], 1);
    atomicAdd(&ddst[dst[t]], 1);
  }
}

// fill xi cols 256..319: node_stats (bf16) + zero pad
__global__ __launch_bounds__(256) void ns_fill(const float* __restrict__ ns,
                                               unsigned short* __restrict__ xi,
                                               int N) {
  int i = blockIdx.x * blockDim.x + threadIdx.x;
  if (i < N * 64) {
    int n = i >> 6, c = i & 63;
    unsigned short v = 0;
    if (c == 0) v = f2bf(ns[(size_t)n * 2 + 0]);
    else if (c == 1) v = f2bf(ns[(size_t)n * 2 + 1]);
    xi[(size_t)n * 320 + 256 + c] = v;
  }
}

// ---------------------------------------------------------------------------
// CSR build: 3-phase parallel exclusive scan, slot scatter.
// ---------------------------------------------------------------------------
__global__ __launch_bounds__(256) void scan_local(
    const int* __restrict__ degA, const int* __restrict__ degB,
    int* __restrict__ rowA, int* __restrict__ rowB, int* __restrict__ bsum,
    int N, int nb) {
  __shared__ int s[256];
  int arr = blockIdx.y;
  const int* deg = arr ? degB : degA;
  int* row = arr ? rowB : rowA;
  int b = blockIdx.x;
  int i = b * 256 + threadIdx.x;
  int v = (i < N) ? deg[i] : 0;
  s[threadIdx.x] = v;
  __syncthreads();
  for (int off = 1; off < 256; off <<= 1) {
    int t = (threadIdx.x >= off) ? s[threadIdx.x - off] : 0;
    __syncthreads();
    s[threadIdx.x] += t;
    __syncthreads();
  }
  int incl = s[threadIdx.x];
  if (i < N) row[i] = incl - v;
  if (threadIdx.x == 255) bsum[arr * nb + b] = incl;
}

__global__ __launch_bounds__(1024) void scan_bsums(int* __restrict__ bsum, int nb,
                                                   int* __restrict__ rowA,
                                                   int* __restrict__ rowB, int N) {
  __shared__ int s[1024];
  int tid = threadIdx.x;
  for (int arr = 0; arr < 2; arr++) {
    int v = (tid < nb) ? bsum[arr * nb + tid] : 0;
    s[tid] = v;
    __syncthreads();
    for (int off = 1; off < 1024; off <<= 1) {
      int t = (tid >= off) ? s[tid - off] : 0;
      __syncthreads();
      s[tid] += t;
      __syncthreads();
    }
    if (tid < nb) bsum[arr * nb + tid] = s[tid] - v;
    if (tid == nb - 1) {
      int* row = arr ? rowB : rowA;
      row[N] = s[tid];
    }
    __syncthreads();
  }
}

__global__ void scan_add(int* __restrict__ rowA, int* __restrict__ rowB,
                         int* __restrict__ curA, const int* __restrict__ bsum,
                         int N, int nb) {
  int arr = blockIdx.y;
  int* row = arr ? rowB : rowA;
  int b = blockIdx.x;
  int i = b * 256 + threadIdx.x;
  if (i < N) {
    int v = row[i] + bsum[arr * nb + b];
    row[i] = v;
    if (arr == 0) curA[i] = v;
  }
}

__global__ void ext_fix(const int* __restrict__ row_dst, int* __restrict__ row_ext,
                        int* __restrict__ cur_ext, int* __restrict__ ext_eid,
                        int* __restrict__ ssrc, int* __restrict__ sdst,
                        int E, int N) {
  int i = blockIdx.x * blockDim.x + threadIdx.x;
  if (i <= N) row_ext[i] = row_dst[i] + i;
  if (i < N) {
    cur_ext[i] = row_dst[i] + i;
    int p = row_dst[i + 1] + i;
    ext_eid[p] = E + i;
    ssrc[p] = i;
    sdst[p] = i;
  }
}

__global__ void scatter_eid(const int* __restrict__ src, const int* __restrict__ dst,
                            int* __restrict__ csrc, int* __restrict__ cext,
                            int* __restrict__ esrc, int* __restrict__ ext_eid,
                            int* __restrict__ ssrc, int* __restrict__ sdst,
                            int E) {
  int t = blockIdx.x * blockDim.x + threadIdx.x;
  if (t < E) {
    int s = src[t], d = dst[t];
    int p = atomicAdd(&csrc[s], 1);
    esrc[p] = t;
    int q = atomicAdd(&cext[d], 1);
    ext_eid[q] = t;
    ssrc[q] = s;
    sdst[q] = d;
  }
}

// ---------------------------------------------------------------------------
// Virtual 3-way concatenated A operand (fp32 sources) — legacy path, unused
// at ABF=1 but kept for the template.
// ---------------------------------------------------------------------------
struct ASrc {
  const float *p0, *p1, *p2;
  int ld0, ld1, ld2, k0, k1;
};
__device__ __forceinline__ float loadA(const ASrc& a, int m, int k) {
  if (k < a.k0) return a.p0[(size_t)m * a.ld0 + k];
  if (k < a.k1) return a.p1[(size_t)m * a.ld1 + (k - a.k0)];
  return a.p2[(size_t)m * a.ld2 + (k - a.k1)];
}
__device__ __forceinline__ int regionOf(const ASrc& a, int k) {
  return k < a.k0 ? 0 : (k < a.k1 ? 1 : 2);
}

// A-staging helper: fills asb[64][72] bf16 for K-chunk kc.
template <int ABF>
__device__ __forceinline__ void stageA(
    const ASrc& A, const unsigned short* __restrict__ Abf, int lda,
    unsigned short* asb, int m0, int kc, int M, int K, int tid) {
  int row = tid & 63, kq = tid >> 6;
  int gm = m0 + row;
  if (ABF) {
    const unsigned short* rp = Abf + (size_t)gm * lda + kc + kq * 16;
    ushort4 z = make_ushort4(0, 0, 0, 0);
#pragma unroll
    for (int q = 0; q < 4; q++) {
      ushort4 v = (gm < M) ? *(const ushort4*)(rp + q * 4) : z;
      *(ushort4*)&asb[row * 72 + kq * 16 + q * 4] = v;
    }
  } else {
    bool fastc = (kc + 64 <= K) && (regionOf(A, kc) == regionOf(A, kc + 63)) &&
                 (gm < M);
    if (fastc) {
      int r = regionOf(A, kc);
      const float* p;
      int ld, koff;
      if (r == 0) { p = A.p0; ld = A.ld0; koff = 0; }
      else if (r == 1) { p = A.p1; ld = A.ld1; koff = A.k0; }
      else { p = A.p2; ld = A.ld2; koff = A.k1; }
      const float* rp = p + (size_t)gm * ld + (kc - koff) + kq * 16;
#pragma unroll
      for (int q = 0; q < 4; q++) {
        float4 v = *(const float4*)(rp + q * 4);
        *(ushort4*)&asb[row * 72 + kq * 16 + q * 4] =
            make_ushort4(f2bf(v.x), f2bf(v.y), f2bf(v.z), f2bf(v.w));
      }
    } else {
#pragma unroll
      for (int q = 0; q < 16; q++) {
        int kk = kc + kq * 16 + q;
        float v = (gm < M && kk < K) ? loadA(A, gm, kk) : 0.f;
        asb[row * 72 + kq * 16 + q] = f2bf(v);
      }
    }
  }
}

// ---------------------------------------------------------------------------
// MFMA GEMM: C[M, n0..n0+128) = act(A[M,K] @ B + bias). 64x128 tile, 4 waves.
// ---------------------------------------------------------------------------
template <int ACT, int OBF, int ABF>
__global__ __launch_bounds__(256) void gemm_mfma(
    ASrc A, const unsigned short* __restrict__ Abf, int lda,
    const unsigned short* __restrict__ Bt, int ldbt,
    const float* __restrict__ bias, void* __restrict__ Cv, int ldc, int M, int K) {
  __shared__ __align__(16) unsigned short asb[64 * 72];
  __shared__ __align__(16) unsigned short bsb[128 * 72];
  int tid = threadIdx.x;
  int m0 = blockIdx.x * 64, n0 = blockIdx.y * 128;
  int lane = tid & 63, wave = tid >> 6;
  int quad = lane >> 4, l16 = lane & 15;
  ffrag zero = {0.f, 0.f, 0.f, 0.f};
  ffrag acc[8];
#pragma unroll
  for (int t = 0; t < 8; t++) acc[t] = zero;
  int KC = (K + 63) & ~63;
  for (int kc = 0; kc < KC; kc += 64) {
    __syncthreads();
    stageA<ABF>(A, Abf, lda, asb, m0, kc, M, K, tid);
    {  // stage B chunk
      int n = tid >> 1, hf = tid & 1;
      const ushort4* rp = (const ushort4*)(Bt + (size_t)(n0 + n) * ldbt + kc + hf * 32);
      ushort4* dp = (ushort4*)&bsb[n * 72 + hf * 32];
#pragma unroll
      for (int i = 0; i < 8; i++) dp[i] = rp[i];
    }
    __syncthreads();
    int arow = wave * 16 + l16;
    bfrag a0 = *(const bfrag*)&asb[arow * 72 + quad * 8];
    bfrag a1 = *(const bfrag*)&asb[arow * 72 + 32 + quad * 8];
#pragma unroll
    for (int t = 0; t < 8; t++) {
      int bn = t * 16 + l16;
      bfrag b0 = *(const bfrag*)&bsb[bn * 72 + quad * 8];
      bfrag b1 = *(const bfrag*)&bsb[bn * 72 + 32 + quad * 8];
      acc[t] = __builtin_amdgcn_mfma_f32_16x16x32_bf16(a0, b0, acc[t], 0, 0, 0);
      acc[t] = __builtin_amdgcn_mfma_f32_16x16x32_bf16(a1, b1, acc[t], 0, 0, 0);
    }
  }
#pragma unroll
  for (int t = 0; t < 8; t++) {
    int col = n0 + t * 16 + l16;
    float bv = bias ? bias[col] : 0.f;
#pragma unroll
    for (int r = 0; r < 4; r++) {
      int row = m0 + wave * 16 + quad * 4 + r;
      if (row < M) {
        float v = acc[t][r] + bv;
        if (ACT == 1) v = fmaxf(v, 0.f);
        if (OBF)
          ((unsigned short*)Cv)[(size_t)row * ldc + col] = f2bf(v);
        else
          ((float*)Cv)[(size_t)row * ldc + col] = v;
      }
    }
  }
}

// ---------------------------------------------------------------------------
// Dual-B MFMA GEMM: stages A once per K-chunk, accumulates A@B1 and A@B2.
// ---------------------------------------------------------------------------
template <int OBF, int ABF>
__global__ __launch_bounds__(256) void gemm_dual(
    ASrc A, const unsigned short* __restrict__ Abf, int lda,
    const unsigned short* __restrict__ Bt1, const unsigned short* __restrict__ Bt2,
    int ldbt, void* __restrict__ Cv1, void* __restrict__ Cv2, int ldc,
    int M, int K) {
  __shared__ __align__(16) unsigned short asb[64 * 72];
  __shared__ __align__(16) unsigned short bsb[128 * 72];
  int tid = threadIdx.x;
  int m0 = blockIdx.x * 64, n0 = blockIdx.y * 128;
  int lane = tid & 63, wave = tid >> 6;
  int quad = lane >> 4, l16 = lane & 15;
  ffrag zero = {0.f, 0.f, 0.f, 0.f};
  ffrag acc1[8], acc2[8];
#pragma unroll
  for (int t = 0; t < 8; t++) { acc1[t] = zero; acc2[t] = zero; }
  int KC = (K + 63) & ~63;
  int arow = wave * 16 + l16;
  for (int kc = 0; kc < KC; kc += 64) {
    __syncthreads();
    stageA<ABF>(A, Abf, lda, asb, m0, kc, M, K, tid);
    {  // stage B1 chunk
      int n = tid >> 1, hf = tid & 1;
      const ushort4* rp = (const ushort4*)(Bt1 + (size_t)(n0 + n) * ldbt + kc + hf * 32);
      ushort4* dp = (ushort4*)&bsb[n * 72 + hf * 32];
#pragma unroll
      for (int i = 0; i < 8; i++) dp[i] = rp[i];
    }
    __syncthreads();
    bfrag a0 = *(const bfrag*)&asb[arow * 72 + quad * 8];
    bfrag a1 = *(const bfrag*)&asb[arow * 72 + 32 + quad * 8];
#pragma unroll
    for (int t = 0; t < 8; t++) {
      int bn = t * 16 + l16;
      bfrag b0 = *(const bfrag*)&bsb[bn * 72 + quad * 8];
      bfrag b1 = *(const bfrag*)&bsb[bn * 72 + 32 + quad * 8];
      acc1[t] = __builtin_amdgcn_mfma_f32_16x16x32_bf16(a0, b0, acc1[t], 0, 0, 0);
      acc1[t] = __builtin_amdgcn_mfma_f32_16x16x32_bf16(a1, b1, acc1[t], 0, 0, 0);
    }
    __syncthreads();  // B1 reads complete before restage
    {  // stage B2 chunk
      int n = tid >> 1, hf = tid & 1;
      const ushort4* rp = (const ushort4*)(Bt2 + (size_t)(n0 + n) * ldbt + kc + hf * 32);
      ushort4* dp = (ushort4*)&bsb[n * 72 + hf * 32];
#pragma unroll
      for (int i = 0; i < 8; i++) dp[i] = rp[i];
    }
    __syncthreads();
#pragma unroll
    for (int t = 0; t < 8; t++) {
      int bn = t * 16 + l16;
      bfrag b0 = *(const bfrag*)&bsb[bn * 72 + quad * 8];
      bfrag b1 = *(const bfrag*)&bsb[bn * 72 + 32 + quad * 8];
      acc2[t] = __builtin_amdgcn_mfma_f32_16x16x32_bf16(a0, b0, acc2[t], 0, 0, 0);
      acc2[t] = __builtin_amdgcn_mfma_f32_16x16x32_bf16(a1, b1, acc2[t], 0, 0, 0);
    }
  }
#pragma unroll
  for (int t = 0; t < 8; t++) {
    int col = n0 + t * 16 + l16;
#pragma unroll
    for (int r = 0; r < 4; r++) {
      int row = m0 + wave * 16 + quad * 4 + r;
      if (row < M) {
        if (OBF) {
          ((unsigned short*)Cv1)[(size_t)row * ldc + col] = f2bf(acc1[t][r]);
          ((unsigned short*)Cv2)[(size_t)row * ldc + col] = f2bf(acc2[t][r]);
        } else {
          ((float*)Cv1)[(size_t)row * ldc + col] = acc1[t][r];
          ((float*)Cv2)[(size_t)row * ldc + col] = acc2[t][r];
        }
      }
    }
  }
}

// ---------------------------------------------------------------------------
// gather-mean, 8B-vectorized; writes bf16 means directly into xi[N][320]
// (side 0 -> cols [0,128), side 1 -> cols [128,256)) and lattrb.
// ---------------------------------------------------------------------------
__global__ __launch_bounds__(256) void gather_mean(
    const int* __restrict__ row_src, const int* __restrict__ eid_src,
    const int* __restrict__ row_ext, const int* __restrict__ ext_eid,
    const unsigned short* __restrict__ emb, const unsigned short* __restrict__ eab,
    unsigned short* __restrict__ xi,
    unsigned short* __restrict__ lattrb, int N) {
  int lane = threadIdx.x & 63, wid = threadIdx.x >> 6;
  int n = blockIdx.x * 4 + wid;
  int side = blockIdx.y;
  if (n >= N) return;
  int lo, hi;
  const int* eid;
  if (side) { lo = row_ext[n]; hi = row_ext[n + 1] - 1; eid = ext_eid; }
  else { lo = row_src[n]; hi = row_src[n + 1]; eid = eid_src; }
  int half = lane >> 5;
  int l32 = lane & 31;
  int c4 = l32 * 4;
  float a0 = 0.f, a1 = 0.f, a2 = 0.f, a3 = 0.f;
  float la0 = 0.f, la1 = 0.f;
  int j = lo;
  for (; j + 1 < hi; j += 2) {
    int e = eid[j + half];
    ushort4 v = *(const ushort4*)&emb[(size_t)e * 128 + c4];
    a0 += bf2f(v.x); a1 += bf2f(v.y); a2 += bf2f(v.z); a3 += bf2f(v.w);
    if (side) {
      ushort2 u = *(const ushort2*)&eab[(size_t)e * 64 + l32 * 2];
      la0 += bf2f(u.x); la1 += bf2f(u.y);
    }
  }
  if (j < hi && half == 0) {  // odd tail: lanes 0-31 only
    int e = eid[j];
    ushort4 v = *(const ushort4*)&emb[(size_t)e * 128 + c4];
    a0 += bf2f(v.x); a1 += bf2f(v.y); a2 += bf2f(v.z); a3 += bf2f(v.w);
    if (side) {
      ushort2 u = *(const ushort2*)&eab[(size_t)e * 64 + l32 * 2];
      la0 += bf2f(u.x); la1 += bf2f(u.y);
    }
  }
  a0 += __shfl_xor(a0, 32);
  a1 += __shfl_xor(a1, 32);
  a2 += __shfl_xor(a2, 32);
  a3 += __shfl_xor(a3, 32);
  if (side) {
    la0 += __shfl_xor(la0, 32);
    la1 += __shfl_xor(la1, 32);
  }
  float r = 1.f / fmaxf((float)(hi - lo), 1.f);
  if (half == 0) {
    *(ushort4*)&xi[(size_t)n * 320 + side * 128 + c4] =
        make_ushort4(f2bf(a0 * r), f2bf(a1 * r), f2bf(a2 * r), f2bf(a3 * r));
    if (side)
      *(ushort2*)&lattrb[(size_t)n * 64 + l32 * 2] =
          make_ushort2(f2bf(la0 * r), f2bf(la1 * r));
  }
}

// ---------------------------------------------------------------------------
// attn_logits_mfma<H> — dst-sorted edges; stores a = exp(min(logit,60)) at
// sorted position j. ssrc/sdst give sequential index reads.
// ---------------------------------------------------------------------------
template <int H>
__global__ __launch_bounds__(256) void attn_logits_mfma(
    const unsigned short* __restrict__ xl, const unsigned short* __restrict__ xr,
    const int* __restrict__ ssrc, const int* __restrict__ sdst,
    const unsigned short* __restrict__ eab, const unsigned short* __restrict__ lattrb,
    const int* __restrict__ ext_eid,
    const unsigned short* __restrict__ wet, const float* __restrict__ att,
    float* __restrict__ lg, int E, int N) {
  constexpr int HC = H * 128;
  __shared__ __align__(16) unsigned short asb[64 * 72];
  __shared__ __align__(16) unsigned short bsb[128 * 72];  // reused as Cs[64][136]
  __shared__ float atts[128];
  __shared__ int sidx[64], didx[64];
  unsigned short* Cs = bsb;
  int tid = threadIdx.x;
  int E2 = E + N;
  int i0 = blockIdx.x * 64;
  int lane = tid & 63, wave = tid >> 6, quad = lane >> 4, l16 = lane & 15;
  if (tid < 64) {
    int j = i0 + tid;
    sidx[tid] = (j < E2) ? ssrc[j] : 0;
    didx[tid] = (j < E2) ? sdst[j] : 0;
  }
  {  // stage A once (bf16 sources, dst-sorted edge order)
    int row = tid & 63, kq = tid >> 6;
    int j = i0 + row;
    if (j < E2) {
      int e = ext_eid[j];
      const unsigned short* ap =
          (e < E) ? eab + (size_t)e * 64 : lattrb + (size_t)(e - E) * 64;
      const ushort4* rp = (const ushort4*)(ap + kq * 16);
#pragma unroll
      for (int q = 0; q < 4; q++)
        *(ushort4*)&asb[row * 72 + kq * 16 + q * 4] = rp[q];
    } else {
      ushort4 z = make_ushort4(0, 0, 0, 0);
#pragma unroll
      for (int q = 0; q < 4; q++) *(ushort4*)&asb[row * 72 + kq * 16 + q * 4] = z;
    }
  }
  int er = tid >> 4, cc = tid & 15;
  ffrag zero = {0.f, 0.f, 0.f, 0.f};
  for (int head = 0; head < H; head++) {
    int n0 = head * 128;
    __syncthreads();
    if (tid < 128) atts[tid] = att[n0 + tid];
    {
      int n = tid >> 1, hf = tid & 1;
      const ushort4* rp = (const ushort4*)(wet + (size_t)(n0 + n) * 64 + hf * 32);
      ushort4* dp = (ushort4*)&bsb[n * 72 + hf * 32];
#pragma unroll
      for (int i = 0; i < 8; i++) dp[i] = rp[i];
    }
    __syncthreads();
    int arow = wave * 16 + l16;
    bfrag a0 = *(const bfrag*)&asb[arow * 72 + quad * 8];
    bfrag a1 = *(const bfrag*)&asb[arow * 72 + 32 + quad * 8];
    ffrag acc[8];
#pragma unroll
    for (int t = 0; t < 8; t++) {
      acc[t] = zero;
      int bn = t * 16 + l16;
      bfrag b0 = *(const bfrag*)&bsb[bn * 72 + quad * 8];
      bfrag b1 = *(const bfrag*)&bsb[bn * 72 + 32 + quad * 8];
      acc[t] = __builtin_amdgcn_mfma_f32_16x16x32_bf16(a0, b0, acc[t], 0, 0, 0);
      acc[t] = __builtin_amdgcn_mfma_f32_16x16x32_bf16(a1, b1, acc[t], 0, 0, 0);
    }
    __syncthreads();
    {
      int rb = wave * 16 + quad * 4;
#pragma unroll
      for (int t = 0; t < 8; t++)
#pragma unroll
        for (int r = 0; r < 4; r++)
          Cs[(rb + r) * 136 + t * 16 + l16] = f2bf(acc[t][r]);
    }
    __syncthreads();
#pragma unroll
    for (int i2 = 0; i2 < 4; i2++) {
      int r = er * 4 + i2;
      int gi = i0 + r;
      float ps = 0.f;
      if (gi < E2) {
        int s = sidx[r], d = didx[r];
#pragma unroll
        for (int h = 0; h < 2; h++) {
          int c = h * 64 + cc * 4;
          ushort4 mv = *(const ushort4*)&Cs[r * 136 + c];
          ushort4 xlu = *(const ushort4*)&xl[(size_t)s * HC + n0 + c];
          ushort4 xru = *(const ushort4*)&xr[(size_t)d * HC + n0 + c];
          float e0 = bf2f(mv.x) + bf2f(xlu.x) + bf2f(xru.x);
          float e1 = bf2f(mv.y) + bf2f(xlu.y) + bf2f(xru.y);
          float e2 = bf2f(mv.z) + bf2f(xlu.z) + bf2f(xru.z);
          float e3 = bf2f(mv.w) + bf2f(xlu.w) + bf2f(xru.w);
          e0 = e0 > 0.f ? e0 : 0.2f * e0;
          e1 = e1 > 0.f ? e1 : 0.2f * e1;
          e2 = e2 > 0.f ? e2 : 0.2f * e2;
          e3 = e3 > 0.f ? e3 : 0.2f * e3;
          ps += e0 * atts[c + 0] + e1 * atts[c + 1] + e2 * atts[c + 2] +
                e3 * atts[c + 3];
        }
      }
      ps += __shfl_xor(ps, 1);
      ps += __shfl_xor(ps, 2);
      ps += __shfl_xor(ps, 4);
      ps += __shfl_xor(ps, 8);
      if (cc == 0 && gi < E2)
        lg[(size_t)gi * H + head] = __expf(fminf(ps, 60.f));
    }
  }
}

// ---------------------------------------------------------------------------
// attn_fused<H> — lg holds pre-exponentiated a at sorted position j; ssrc
// gives the source node sequentially.
// ---------------------------------------------------------------------------
template <int H>
__global__ __launch_bounds__(256) void attn_fused(
    const unsigned short* __restrict__ xl, const float* __restrict__ lg,
    const int* __restrict__ row_ext, const int* __restrict__ ssrc,
    const float* __restrict__ bias,
    const float* __restrict__ gam, const float* __restrict__ bet,
    unsigned short* __restrict__ hout, int E, int N) {
  constexpr int HC = H * 128;
  constexpr int CPL = HC / 64;
  int lane = threadIdx.x & 63, wid = threadIdx.x >> 6;
  int n = blockIdx.x * 4 + wid;
  if (n >= N) return;
  int lo = row_ext[n], hi = row_ext[n + 1];
  int myh = (H == 2) ? (lane >> 5) : 0;
  int colbase = (H == 2) ? (myh * 128 + (lane & 31) * 4) : (lane * 2);
  float asum = 0.f;
  float acc[CPL] = {};
  for (int j = lo; j < hi; j++) {
    int s = ssrc[j];
    float a = lg[(size_t)j * H + myh];
    asum += a;
    const unsigned short* xp = &xl[(size_t)s * HC + colbase];
    if (H == 2) {
      ushort4 u = *(const ushort4*)xp;
      acc[0] += a * bf2f(u.x);
      acc[1] += a * bf2f(u.y);
      acc[2] += a * bf2f(u.z);
      acc[3] += a * bf2f(u.w);
    } else {
      ushort2 u = *(const ushort2*)xp;
      acc[0] += a * bf2f(u.x);
      acc[1] += a * bf2f(u.y);
    }
  }
  float inv = 1.f / fmaxf(asum, 1e-16f);
#pragma unroll
  for (int k = 0; k < CPL; k++) acc[k] *= inv;
  int ch;
  if (H == 2) {
#pragma unroll
    for (int k = 0; k < CPL; k++) acc[k] = (acc[k] + __shfl_xor(acc[k], 32)) * 0.5f;
    ch = (lane & 31) * CPL;
  } else {
    ch = lane * CPL;
  }
#pragma unroll
  for (int k = 0; k < CPL; k++) acc[k] += bias[ch + k];
  float s = 0.f;
#pragma unroll
  for (int k = 0; k < CPL; k++) s += acc[k];
#pragma unroll
  for (int mm = 1; mm < 64; mm <<= 1) s += __shfl_xor(s, mm);
  constexpr float dupn = (H == 2) ? 256.f : 128.f;
  float mu = s / dupn;
  float vs = 0.f;
#pragma unroll
  for (int k = 0; k < CPL; k++) {
    acc[k] -= mu;
    vs += acc[k] * acc[k];
  }
#pragma unroll
  for (int mm = 1; mm < 64; mm <<= 1) vs += __shfl_xor(vs, mm);
  float rstd = rsqrtf(vs / dupn + 1e-5f);
  float y[CPL];
#pragma unroll
  for (int k = 0; k < CPL; k++) {
    float v = acc[k] * rstd * gam[ch + k] + bet[ch + k];
    y[k] = v > 0.f ? v : expm1f(v);
  }
  if (H == 2) {
    if (lane < 32)
      *(ushort4*)&hout[(size_t)n * 128 + ch] =
          make_ushort4(f2bf(y[0]), f2bf(y[1]), f2bf(y[2]), f2bf(y[3]));
  } else {
    *(ushort2*)&hout[(size_t)n * 128 + ch] = make_ushort2(f2bf(y[0]), f2bf(y[1]));
  }
}

// ---------------------------------------------------------------------------
// classifier_mfma — fully fused + LDS union arena (37KB): phases {asb,bsb}
// alias epilogue {t1s,c2s}. c1 = ea@c1wc + h2[s]@c1wa + h2[d]@c1wb, then
// relu -> c2 -> relu -> c3. src-sorted edges; out scattered via eidx.
// ---------------------------------------------------------------------------
__global__ __launch_bounds__(256) void classifier_mfma(
    const unsigned short* __restrict__ eab, const unsigned short* __restrict__ h2b,
    const int* __restrict__ eid_src,
    const int* __restrict__ src, const int* __restrict__ dst,
    const unsigned short* __restrict__ c1wct, const unsigned short* __restrict__ c1wat,
    const unsigned short* __restrict__ c1wbt,
    const float* __restrict__ c1b, const unsigned short* __restrict__ c2t,
    const float* __restrict__ c2b, const float* __restrict__ c3w,
    const float* __restrict__ c3b, float* __restrict__ out, int E) {
  __shared__ __align__(16) unsigned char arena[34816];
  unsigned short* asb = (unsigned short*)arena;             // [64*72]
  unsigned short* bsb = (unsigned short*)(arena + 9216);    // [128*72]
  unsigned short* t1s = (unsigned short*)arena;             // [64*136]
  unsigned short* c2s = (unsigned short*)(arena + 17408);   // [64*136]
  __shared__ float c1bs[128];
  __shared__ float c2bs[64], c3ws[64];
  __shared__ int sidx[64], didx[64], eidx[64];
  int tid = threadIdx.x;
  int e0 = blockIdx.x * 64;
  int lane = tid & 63, wave = tid >> 6, quad = lane >> 4, l16 = lane & 15;
  if (tid < 128) c1bs[tid] = c1b[tid];
  if (tid < 64) {
    c2bs[tid] = c2b[tid];
    c3ws[tid] = c3w[tid];
    int j = e0 + tid;
    int e = (j < E) ? eid_src[j] : -1;
    eidx[tid] = e;
    sidx[tid] = (e >= 0) ? src[e] : 0;
    didx[tid] = (e >= 0) ? dst[e] : 0;
  }
  ffrag zero = {0.f, 0.f, 0.f, 0.f};
  ffrag acc[8];
#pragma unroll
  for (int t = 0; t < 8; t++) acc[t] = zero;
  int arow = wave * 16 + l16;
  // ---- phase 1: ea @ c1wc (K=64) ----
  {
    int row = tid & 63, kq = tid >> 6;
    int j = e0 + row;
    if (j < E) {
      int e = eid_src[j];
      const ushort4* rp = (const ushort4*)(eab + (size_t)e * 64 + kq * 16);
#pragma unroll
      for (int q = 0; q < 4; q++)
        *(ushort4*)&asb[row * 72 + kq * 16 + q * 4] = rp[q];
    } else {
      ushort4 z = make_ushort4(0, 0, 0, 0);
#pragma unroll
      for (int q = 0; q < 4; q++) *(ushort4*)&asb[row * 72 + kq * 16 + q * 4] = z;
    }
    int n = tid >> 1, hf = tid & 1;
    const ushort4* rp2 = (const ushort4*)(c1wct + (size_t)n * 64 + hf * 32);
    ushort4* dp = (ushort4*)&bsb[n * 72 + hf * 32];
#pragma unroll
    for (int i = 0; i < 8; i++) dp[i] = rp2[i];
  }
  __syncthreads();
  {
    bfrag a0 = *(const bfrag*)&asb[arow * 72 + quad * 8];
    bfrag a1 = *(const bfrag*)&asb[arow * 72 + 32 + quad * 8];
#pragma unroll
    for (int t = 0; t < 8; t++) {
      int bn = t * 16 + l16;
      bfrag b0 = *(const bfrag*)&bsb[bn * 72 + quad * 8];
      bfrag b1 = *(const bfrag*)&bsb[bn * 72 + 32 + quad * 8];
      acc[t] = __builtin_amdgcn_mfma_f32_16x16x32_bf16(a0, b0, acc[t], 0, 0, 0);
      acc[t] = __builtin_amdgcn_mfma_f32_16x16x32_bf16(a1, b1, acc[t], 0, 0, 0);
    }
  }
  // ---- phases 2,3: h2[s]@c1wa, h2[d]@c1wb — K=128, staged in 64-col halves ----
  for (int ph = 0; ph < 2; ph++) {
    const int* idx = ph ? didx : sidx;
    const unsigned short* Wt = ph ? c1wbt : c1wat;
#pragma unroll
    for (int kc = 0; kc < 2; kc++) {
      __syncthreads();  // prior MFMA reads of asb/bsb complete
      {  // stage A half: h2[idx][kc*64 .. +64)  (128B gather per row)
        int row = tid & 63, kq = tid >> 6;
        int s = idx[row];
        const ushort4* rp =
            (const ushort4*)(h2b + (size_t)s * 128 + kc * 64 + kq * 16);
#pragma unroll
        for (int q = 0; q < 4; q++)
          *(ushort4*)&asb[row * 72 + kq * 16 + q * 4] = rp[q];
        // stage B half: Wt[n][kc*64 .. +64)
        int n = tid >> 1, hf = tid & 1;
        const ushort4* rp2 =
            (const ushort4*)(Wt + (size_t)n * 128 + kc * 64 + hf * 32);
        ushort4* dp = (ushort4*)&bsb[n * 72 + hf * 32];
#pragma unroll
        for (int i = 0; i < 8; i++) dp[i] = rp2[i];
      }
      __syncthreads();
      bfrag a0 = *(const bfrag*)&asb[arow * 72 + quad * 8];
      bfrag a1 = *(const bfrag*)&asb[arow * 72 + 32 + quad * 8];
#pragma unroll
      for (int t = 0; t < 8; t++) {
        int bn = t * 16 + l16;
        bfrag b0 = *(const bfrag*)&bsb[bn * 72 + quad * 8];
        bfrag b1 = *(const bfrag*)&bsb[bn * 72 + 32 + quad * 8];
        acc[t] = __builtin_amdgcn_mfma_f32_16x16x32_bf16(a0, b0, acc[t], 0, 0, 0);
        acc[t] = __builtin_amdgcn_mfma_f32_16x16x32_bf16(a1, b1, acc[t], 0, 0, 0);
      }
    }
  }
  __syncthreads();  // phase reads done; arena repartitioned as t1s/c2s
  // ---- c1 epilogue -> t1s bf16; stage c2t into c2s ----
  {
    int rb = wave * 16 + quad * 4;
#pragma unroll
    for (int t = 0; t < 8; t++) {
      int col = t * 16 + l16;
#pragma unroll
      for (int r = 0; r < 4; r++) {
        float v = acc[t][r] + c1bs[col];
        t1s[(rb + r) * 136 + col] = f2bf(fmaxf(v, 0.f));
      }
    }
    int n = tid >> 2, qq = tid & 3;
    const ushort4* rp = (const ushort4*)(c2t + (size_t)n * 128 + qq * 32);
    ushort4* dp = (ushort4*)&c2s[n * 136 + qq * 32];
#pragma unroll
    for (int i = 0; i < 8; i++) dp[i] = rp[i];
  }
  __syncthreads();
  {
    bfrag pa[4];
#pragma unroll
    for (int kc = 0; kc < 4; kc++)
      pa[kc] = *(const bfrag*)&t1s[arow * 136 + kc * 32 + quad * 8];
    ffrag acc2[4];
#pragma unroll
    for (int t = 0; t < 4; t++) {
      acc2[t] = zero;
      int bn = t * 16 + l16;
#pragma unroll
      for (int kc = 0; kc < 4; kc++) {
        bfrag b = *(const bfrag*)&c2s[bn * 136 + kc * 32 + quad * 8];
        acc2[t] = __builtin_amdgcn_mfma_f32_16x16x32_bf16(pa[kc], b, acc2[t], 0, 0, 0);
      }
    }
    float c3b0 = c3b[0];
    float rsum[4] = {0.f, 0.f, 0.f, 0.f};
#pragma unroll
    for (int t = 0; t < 4; t++) {
      int col = t * 16 + l16;
      float cb = c2bs[col], cw = c3ws[col];
#pragma unroll
      for (int r = 0; r < 4; r++)
        rsum[r] += fmaxf(acc2[t][r] + cb, 0.f) * cw;
    }
#pragma unroll
    for (int r = 0; r < 4; r++) {
      rsum[r] += __shfl_xor(rsum[r], 1);
      rsum[r] += __shfl_xor(rsum[r], 2);
      rsum[r] += __shfl_xor(rsum[r], 4);
      rsum[r] += __shfl_xor(rsum[r], 8);
    }
    if (l16 == 0) {
#pragma unroll
      for (int r = 0; r < 4; r++) {
        int e = eidx[wave * 16 + quad * 4 + r];
        if (e >= 0) out[e] = rsum[r] + c3b0;
      }
    }
  }
}

// ---------------------------------------------------------------------------
extern "C" void kernel_launch(void* const* d_in, const int* in_sizes, int n_in,
                              void* d_out, int out_size, void* d_ws, size_t ws_size,
                              hipStream_t stream) {
  const int N = in_sizes[1] / 2;   // node_stats [N,2]
  const int E = in_sizes[3] / 64;  // edge_attr [E,64]
  const int E2 = E + N;
  const int nb = cdiv(N, 256);     // scan blocks per array (<=1024)

  const float* node_stats = (const float*)d_in[1];
  const int* src = (const int*)d_in[2];
  const int* dst = (const int*)d_in[2] + E;
  const float* edge_attr = (const float*)d_in[3];
  const float* epw = (const float*)d_in[4];
  const float* epb = (const float*)d_in[5];
  const float* g1wl = (const float*)d_in[6];
  const float* g1wr = (const float*)d_in[7];
  const float* g1we = (const float*)d_in[8];
  const float* g1att = (const float*)d_in[9];
  const float* g1b = (const float*)d_in[10];
  const float* n1g = (const float*)d_in[11];
  const float* n1b = (const float*)d_in[12];
  const float* g2wl = (const float*)d_in[13];
  const float* g2wr = (const float*)d_in[14];
  const float* g2we = (const float*)d_in[15];
  const float* g2att = (const float*)d_in[16];
  const float* g2b = (const float*)d_in[17];
  const float* n2g = (const float*)d_in[18];
  const float* n2b = (const float*)d_in[19];
  const float* c1w = (const float*)d_in[20];
  const float* c1b = (const float*)d_in[21];
  const float* c2w = (const float*)d_in[22];
  const float* c2b = (const float*)d_in[23];
  const float* c3w = (const float*)d_in[24];
  const float* c3b = (const float*)d_in[25];
  float* out = (float*)d_out;

  // workspace arena (float units)
  float* w = (float*)d_ws;
  size_t o = 0;
  auto alloc = [&](size_t n) { float* p = w + o; o += n; return p; };
  unsigned short* xi = (unsigned short*)alloc((size_t)N * 160);  // bf16 [N][320]
  float* lattr = alloc((size_t)N * 64);  // used as bf16 [N][64]
  float* lg = alloc((size_t)E2 * 2);
  int* row_src = (int*)alloc((size_t)(N + 1));
  int* row_dst = (int*)alloc((size_t)(N + 1));
  int* row_ext = (int*)alloc((size_t)(N + 1));
  int* deg_src = (int*)alloc((size_t)N);  // deg pair contiguous (memset)
  int* deg_dst = (int*)alloc((size_t)N);
  int* cur_src = (int*)alloc((size_t)N);
  int* cur_ext = (int*)alloc((size_t)N);
  int* eid_src = (int*)alloc((size_t)E);
  int* ext_eid = (int*)alloc((size_t)E2);
  int* ssrc = (int*)alloc((size_t)E2);
  int* sdst = (int*)alloc((size_t)E2);
  int* bsum = (int*)alloc((size_t)2 * 1024);
  unsigned short* wb = (unsigned short*)alloc(140000);  // bf16 weight arena
  unsigned short* eab = (unsigned short*)alloc((size_t)E * 32);  // edge_attr bf16
  float* R = alloc((size_t)E * 64);  // bf16 feature arena (E*128 ushorts)
  unsigned short* Ru = (unsigned short*)R;
  unsigned short* emb = Ru;                                // E*128
  unsigned short* xl1b = Ru;                               // N*256 (emb dead)
  unsigned short* xr1b = Ru + (size_t)N * 256;             // N*256
  unsigned short* h1b = Ru + (size_t)N * 512;              // N*128
  unsigned short* xl2b = Ru + (size_t)N * 640;             // N*128
  unsigned short* xr2b = Ru + (size_t)N * 768;             // N*128
  unsigned short* h2b = Ru + (size_t)N * 896;              // N*128
  unsigned short* lattrb = (unsigned short*)lattr;

  // bf16 transposed weights
  unsigned short* epwt = wb + 0;        // [128][64]
  unsigned short* g1wlt = wb + 8192;    // [256][320]
  unsigned short* g1wrt = wb + 90112;   // [256][320]
  unsigned short* g1wet = wb + 172032;  // [256][64]
  unsigned short* g2wlt = wb + 188416;  // [128][128]
  unsigned short* g2wrt = wb + 204800;  // [128][128]
  unsigned short* g2wet = wb + 221184;  // [128][64]
  unsigned short* c1wat = wb + 229376;  // [128][128]
  unsigned short* c1wbt = wb + 245760;  // [128][128]
  unsigned short* c1wct = wb + 262144;  // [128][64]
  unsigned short* c2t = wb + 270336;    // [64][128]

  // ---- stage -1: edge_attr bf16 + degree count (merged) + weight prep ----
  hipMemsetAsync(deg_src, 0, (size_t)2 * N * sizeof(int), stream);
  cvt_cnt<<<2048, 256, 0, stream>>>(edge_attr, eab, E * 16, src, dst, deg_src,
                                    deg_dst, E);
  PrepJobs J;
  auto setj = [&](int i, const float* s, unsigned short* d2, int K, int Nc,
                  int KC, int ld) {
    J.src[i] = s; J.dst[i] = d2; J.K[i] = K; J.Nc[i] = Nc; J.KC[i] = KC; J.ld[i] = ld;
  };
  setj(0, epw, epwt, 64, 128, 64, 128);
  setj(1, g1wl, g1wlt, 258, 256, 320, 256);
  setj(2, g1wr, g1wrt, 258, 256, 320, 256);
  setj(3, g1we, g1wet, 64, 256, 64, 256);
  setj(4, g2wl, g2wlt, 128, 128, 128, 128);
  setj(5, g2wr, g2wrt, 128, 128, 128, 128);
  setj(6, g2we, g2wet, 64, 128, 64, 128);
  setj(7, c1w, c1wat, 128, 128, 128, 128);
  setj(8, c1w + 128 * 128, c1wbt, 128, 128, 128, 128);
  setj(9, c1w + 256 * 128, c1wct, 64, 128, 64, 128);
  setj(10, c2w, c2t, 128, 64, 128, 64);
  prep_bt<<<dim3(11, 32), 256, 0, stream>>>(J);
  ns_fill<<<cdiv(N * 64, 256), 256, 0, stream>>>(node_stats, xi, N);

  // ---- stage 0: CSR (src) + extended dst CSR (parallel scan) ----
  scan_local<<<dim3(nb, 2), 256, 0, stream>>>(deg_src, deg_dst, row_src, row_dst,
                                              bsum, N, nb);
  scan_bsums<<<1, 1024, 0, stream>>>(bsum, nb, row_src, row_dst, N);
  scan_add<<<dim3(nb, 2), 256, 0, stream>>>(row_src, row_dst, cur_src, bsum, N, nb);
  ext_fix<<<cdiv(N + 1, 256), 256, 0, stream>>>(row_dst, row_ext, cur_ext,
                                                ext_eid, ssrc, sdst, E, N);
  scatter_eid<<<cdiv(E, 256), 256, 0, stream>>>(src, dst, cur_src, cur_ext,
                                                eid_src, ext_eid, ssrc, sdst, E);

  ASrc dummy{nullptr, nullptr, nullptr, 0, 0, 0, 0, 0};

  // ---- stage 1: emb = relu(ea@epw+epb) bf16; gather means -> xi bf16 ----
  gemm_mfma<1, 1, 1><<<dim3(cdiv(E, 64), 1), 256, 0, stream>>>(
      dummy, eab, 64, epwt, 64, epb, emb, 128, E, 64);
  gather_mean<<<dim3(cdiv(N, 4), 2), 256, 0, stream>>>(
      row_src, eid_src, row_ext, ext_eid, emb, eab, xi, lattrb, N);

  // ---- stage 2: xl1/xr1 (bf16) = xi @ g1wl / g1wr — dual-B, bf16 A ----
  {
    dim3 g(cdiv(N, 64), 2);
    gemm_dual<1, 1><<<g, 256, 0, stream>>>(dummy, xi, 320, g1wlt, g1wrt, 320,
                                           xl1b, xr1b, 256, N, 258);
  }

  // ---- stage 3: GATv2 layer 1 (H=2) ----
  attn_logits_mfma<2><<<cdiv(E2, 64), 256, 0, stream>>>(
      xl1b, xr1b, ssrc, sdst, eab, lattrb, ext_eid, g1wet, g1att, lg, E, N);
  attn_fused<2><<<cdiv(N, 4), 256, 0, stream>>>(xl1b, lg, row_ext, ssrc,
                                                g1b, n1g, n1b, h1b, E, N);

  // ---- stage 4: xl2/xr2 (bf16) = h1 @ g2wl / g2wr — dual-B ----
  {
    dim3 g(cdiv(N, 64), 1);
    gemm_dual<1, 1><<<g, 256, 0, stream>>>(dummy, h1b, 128, g2wlt, g2wrt, 128,
                                           xl2b, xr2b, 128, N, 128);
  }

  // ---- stage 5: GATv2 layer 2 (H=1) ----
  attn_logits_mfma<1><<<cdiv(E2, 64), 256, 0, stream>>>(
      xl2b, xr2b, ssrc, sdst, eab, lattrb, ext_eid, g2wet, g2att, lg, E, N);
  attn_fused<1><<<cdiv(N, 4), 256, 0, stream>>>(xl2b, lg, row_ext, ssrc,
                                                g2b, n2g, n2b, h2b, E, N);

  // ---- stage 6: classifier, fully fused (union-arena LDS) ----
  classifier_mfma<<<cdiv(E, 64), 256, 0, stream>>>(
      eab, h2b, eid_src, src, dst, c1wct, c1wat, c1wbt, c1b, c2t, c2b, c3w,
      c3b, out, E);
}